// Round 5
// baseline (664.895 us; speedup 1.0000x reference)
//
#include <hip/hip_runtime.h>

// ---------------------------------------------------------------------------
// GNNWithPrompt, f32 I/O. Hi-only bf16 activations, hi+lo bf16 weights.
// All GEMMs are LDS-free / barrier-free: B lives in per-wave registers
// (each wave owns 16-32 output cols), A is loaded from global directly in
// MFMA fragment layout. Classifier fused into layer-1 GEMM epilogue.
// 9 dispatches total.
// ---------------------------------------------------------------------------

#define N0v 200000
#define N1v 50000
#define N2v 10000
#define E0v 800000
#define E1v 160000

using u16 = unsigned short;
typedef __attribute__((ext_vector_type(8))) short short8;
typedef __attribute__((ext_vector_type(4))) float f32x4;

__device__ __forceinline__ float b2f(u16 u) {
    union { unsigned int i; float f; } v; v.i = ((unsigned int)u) << 16; return v.f;
}
__device__ __forceinline__ u16 f2b(float f) {  // round-to-nearest-even
    union { float f; unsigned int i; } v; v.f = f;
    return (u16)((v.i + 0x7fffu + ((v.i >> 16) & 1u)) >> 16);
}
__device__ __forceinline__ void split2(float f, u16& h, u16& l) {
    h = f2b(f);
    l = f2b(f - b2f(h));
}

// --- prep: mask detect + weight hi/lo splits + out=bias init ---------------
__global__ void k_prep(const unsigned* mask, int* flag,
                       const float* w_pin, const float* w_pout, u16* WTph, u16* WTpl,
                       const float* ws0, const float* wn0, u16* WT0h, u16* WT0l,
                       const float* ws1, const float* wn1, u16* WT1h, u16* WT1l,
                       const float* bc, float* outp) {
    const int R0 = 50000;             // detect words
    const int R1 = R0 + 128 * 128;    // prompt WT
    const int R2 = R1 + 256 * 384;    // layer0 WT
    const int R3 = R2 + 256 * 512;    // layer1 WT
    const int R4 = R3 + 2 * N2v;      // out bias init
    for (int i = blockIdx.x * blockDim.x + threadIdx.x; i < R4;
         i += gridDim.x * blockDim.x) {
        if (i < R0) {
            if (mask[i] > 1u) atomicOr(flag, 1);
        } else if (i < R1) {
            int j = i - R0, n = j >> 7, k = j & 127;
            float f = (n < 64) ? w_pin[k * 64 + n] : w_pout[k * 64 + (n - 64)];
            split2(f, WTph[j], WTpl[j]);
        } else if (i < R2) {
            int j = i - R1, n = j / 384, k = j % 384;
            float f = (k < 192) ? ws0[k * 256 + n] : wn0[(k - 192) * 256 + n];
            split2(f, WT0h[j], WT0l[j]);
        } else if (i < R3) {
            int j = i - R2, n = j >> 9, k = j & 511;
            float f = (k < 256) ? ws1[k * 256 + n] : wn1[(k - 256) * 256 + n];
            split2(f, WT1h[j], WT1l[j]);
        } else {
            int j = i - R3;
            outp[j] = bc[j & 1];
        }
    }
}

// --- CSR build: both graphs per dispatch -----------------------------------
__global__ void k_count2(const int* __restrict__ dst0, const int* __restrict__ dst1,
                         int* cnt0, int* cnt1) {
    for (int i = blockIdx.x * blockDim.x + threadIdx.x; i < E0v + E1v;
         i += gridDim.x * blockDim.x) {
        if (i < E0v) atomicAdd(&cnt0[dst0[i]], 1);
        else         atomicAdd(&cnt1[dst1[i - E0v]], 1);
    }
}

__device__ void scan_body(const int* __restrict__ cnt, int* __restrict__ off, int n) {
    __shared__ int lds[1024];
    int t = threadIdx.x;
    int chunk = (n + 1023) >> 10;
    int b = t * chunk, e = b + chunk;
    if (e > n) e = n;
    int s = 0;
    for (int i = b; i < e; i++) s += cnt[i];
    lds[t] = s;
    __syncthreads();
    for (int d = 1; d < 1024; d <<= 1) {
        int v = (t >= d) ? lds[t - d] : 0;
        __syncthreads();
        lds[t] += v;
        __syncthreads();
    }
    int run = lds[t] - s;
    for (int i = b; i < e; i++) { off[i] = run; run += cnt[i]; }
    if (t == 1023) off[n] = lds[1023];
}

__global__ __launch_bounds__(1024) void k_scan2(const int* cnt0, int* off0,
                                                const int* cnt1, int* off1) {
    if (blockIdx.x == 0) scan_body(cnt0, off0, N1v);
    else                 scan_body(cnt1, off1, N2v);
}

__global__ void k_scatter2(const int* __restrict__ src0, const int* __restrict__ dst0,
                           const int* __restrict__ off0, int* cur0, int* ei0,
                           const int* __restrict__ src1, const int* __restrict__ dst1,
                           const int* __restrict__ off1, int* cur1, int* ei1) {
    for (int i = blockIdx.x * blockDim.x + threadIdx.x; i < E0v + E1v;
         i += gridDim.x * blockDim.x) {
        if (i < E0v) {
            int d = dst0[i];
            ei0[off0[d] + atomicAdd(&cur0[d], 1)] = src0[i];
        } else {
            int d = dst1[i - E0v];
            ei1[off1[d] + atomicAdd(&cur1[d], 1)] = src1[i - E0v];
        }
    }
}

// ---------------------------------------------------------------------------
// Prompt GEMM, LDS-free: M=200000 (64 rows/block), K=128, N=128.
// Wave w owns cols w*32..w*32+31 (2 n-tiles); B frags in registers.
// A f32 loaded in frag layout, converted; wave 0 side-stores featH into G.
// Epilogue: relu+mask-select -> G[:,128:192].
// ---------------------------------------------------------------------------
__global__ __launch_bounds__(256, 2) void k_gemm_p(
    const float* __restrict__ A, const u16* __restrict__ Bh, const u16* __restrict__ Bl,
    const float* __restrict__ b_pin, const float* __restrict__ b_pout,
    const void* maskp, const int* __restrict__ flag, u16* __restrict__ G) {
    const int t = threadIdx.x;
    const int lane = t & 63, w = t >> 6;
    const int m = lane & 15, q = lane >> 4;
    const int r0 = blockIdx.x * 64;
    const int n0 = w * 32;

    short8 bf[2][4][2];
#pragma unroll
    for (int nt = 0; nt < 2; nt++)
#pragma unroll
        for (int k0 = 0; k0 < 4; k0++) {
            size_t b = (size_t)(n0 + nt * 16 + m) * 128 + k0 * 32 + q * 8;
            bf[nt][k0][0] = *(const short8*)&Bh[b];
            bf[nt][k0][1] = *(const short8*)&Bl[b];
        }

    f32x4 acc[4][2] = {};
#pragma unroll
    for (int mi = 0; mi < 4; mi++) {
        const int row = r0 + mi * 16 + m;
#pragma unroll
        for (int k0 = 0; k0 < 4; k0++) {
            const float* ap = &A[(size_t)row * 128 + k0 * 32 + q * 8];
            float4 v0 = *(const float4*)ap, v1 = *(const float4*)(ap + 4);
            u16 h8[8];
            h8[0] = f2b(v0.x); h8[1] = f2b(v0.y); h8[2] = f2b(v0.z); h8[3] = f2b(v0.w);
            h8[4] = f2b(v1.x); h8[5] = f2b(v1.y); h8[6] = f2b(v1.z); h8[7] = f2b(v1.w);
            if (w == 0)
                *(uint4*)&G[(size_t)row * 192 + k0 * 32 + q * 8] = *(const uint4*)h8;
            short8 af = *(const short8*)h8;
#pragma unroll
            for (int nt = 0; nt < 2; nt++) {
                acc[mi][nt] = __builtin_amdgcn_mfma_f32_16x16x32_bf16(af, bf[nt][k0][0], acc[mi][nt], 0, 0, 0);
                acc[mi][nt] = __builtin_amdgcn_mfma_f32_16x16x32_bf16(af, bf[nt][k0][1], acc[mi][nt], 0, 0, 0);
            }
        }
    }

    const int fl = *flag;
#pragma unroll
    for (int mi = 0; mi < 4; mi++) {
#pragma unroll
        for (int nt = 0; nt < 2; nt++) {
            int col = n0 + nt * 16 + m;
            float bv = (col < 64) ? b_pin[col] : b_pout[col - 64];
#pragma unroll
            for (int r = 0; r < 4; r++) {
                int row = r0 + mi * 16 + q * 4 + r;
                bool mk = fl ? (((const unsigned char*)maskp)[row] != 0)
                             : (((const int*)maskp)[row] != 0);
                if (mk == (col < 64)) {
                    float v = acc[mi][nt][r] + bv;
                    v = v > 0.f ? v : 0.f;
                    G[(size_t)row * 192 + 128 + (col & 63)] = f2b(v);
                }
            }
        }
    }
}

// ---------------------------------------------------------------------------
// Direct GEMM, LDS-free: 64 rows/block, 64 cols/block (wave owns 16 cols).
// A = bf16, 2 K-segments. B frags in registers (KT k-steps).
// MODE 1: relu -> bf16 CH[M,256].  MODE 3: fused classifier:
//   out[row,c] += sum_cols (acc+bias)*wc[col][c]  (atomic partials).
// ---------------------------------------------------------------------------
template <int MODE, int KT, int KE0>
__global__ __launch_bounds__(256, 2) void k_dgemm(
    const u16* __restrict__ A0, int s0,
    const u16* __restrict__ A1, int s1,
    const u16* __restrict__ Bh, const u16* __restrict__ Bl,
    const float* __restrict__ bias,
    u16* __restrict__ CH, float* __restrict__ outp, const float* __restrict__ wc,
    int M) {
    const int t = threadIdx.x;
    const int lane = t & 63, w = t >> 6;
    const int m = lane & 15, q = lane >> 4;
    const int r0 = blockIdx.x * 64;
    const int col = blockIdx.y * 64 + w * 16 + m;
    const int K = KT * 32;

    short8 bf[KT][2];
#pragma unroll
    for (int k0 = 0; k0 < KT; k0++) {
        size_t b = (size_t)col * K + k0 * 32 + q * 8;
        bf[k0][0] = *(const short8*)&Bh[b];
        bf[k0][1] = *(const short8*)&Bl[b];
    }

    f32x4 acc[4] = {};
#pragma unroll
    for (int mi = 0; mi < 4; mi++) {
        int row = r0 + mi * 16 + m;
        if (row >= M) row = M - 1;
#pragma unroll
        for (int k0 = 0; k0 < KT; k0++) {
            short8 af;
            if (k0 < KE0)
                af = *(const short8*)&A0[(size_t)row * s0 + k0 * 32 + q * 8];
            else
                af = *(const short8*)&A1[(size_t)row * s1 + (k0 - KE0) * 32 + q * 8];
            acc[mi] = __builtin_amdgcn_mfma_f32_16x16x32_bf16(af, bf[k0][0], acc[mi], 0, 0, 0);
            acc[mi] = __builtin_amdgcn_mfma_f32_16x16x32_bf16(af, bf[k0][1], acc[mi], 0, 0, 0);
        }
    }

    const float bv = bias[col];
    if (MODE == 1) {
#pragma unroll
        for (int mi = 0; mi < 4; mi++) {
#pragma unroll
            for (int r = 0; r < 4; r++) {
                int row = r0 + mi * 16 + q * 4 + r;
                if (row < M) {
                    float v = acc[mi][r] + bv;
                    v = v > 0.f ? v : 0.f;
                    CH[(size_t)row * 256 + col] = f2b(v);
                }
            }
        }
    } else {
        const float w0 = wc[col * 2], w1 = wc[col * 2 + 1];
#pragma unroll
        for (int mi = 0; mi < 4; mi++) {
#pragma unroll
            for (int r = 0; r < 4; r++) {
                int row = r0 + mi * 16 + q * 4 + r;
                float v = acc[mi][r] + bv;
                float p0 = v * w0, p1 = v * w1;
#pragma unroll
                for (int s = 1; s < 16; s <<= 1) {
                    p0 += __shfl_xor(p0, s);
                    p1 += __shfl_xor(p1, s);
                }
                if (m == 0 && row < M) {
                    atomicAdd(&outp[row * 2], p0);
                    atomicAdd(&outp[row * 2 + 1], p1);
                }
            }
        }
    }
}

// --- layer-0 mean-agg: wave/dst over G rows (384 B), index broadcast -------
__global__ void k_agg0(const u16* __restrict__ G, const int* __restrict__ off,
                       const int* __restrict__ eidx, u16* __restrict__ aggH) {
    int wid = (blockIdx.x * blockDim.x + threadIdx.x) >> 6;
    int lane = threadIdx.x & 63;
    if (wid >= N1v) return;
    int b = off[wid], e = off[wid + 1];
    float f0 = 0.f, f1 = 0.f, p0 = 0.f;
    for (int base = b; base < e; base += 64) {
        int li = base + lane;
        int idx = eidx[li < e ? li : (e - 1)];
        int nch = e - base; if (nch > 64) nch = 64;
        for (int j = 0; j < nch; j++) {
            int s = __shfl(idx, j);
            const u16* row = &G[(size_t)s * 192];
            unsigned fv = *(const unsigned*)&row[2 * lane];
            u16 pv = row[128 + lane];
            f0 += b2f((u16)fv);
            f1 += b2f((u16)(fv >> 16));
            p0 += b2f(pv);
        }
    }
    int deg = e - b;
    float inv = 1.0f / (float)(deg > 1 ? deg : 1);
    size_t rb = (size_t)wid * 192;
    *(unsigned*)&aggH[rb + 2 * lane] =
        (unsigned)f2b(f0 * inv) | ((unsigned)f2b(f1 * inv) << 16);
    aggH[rb + 128 + lane] = f2b(p0 * inv);
}

// --- layer-1 mean-agg: wave/dst over h1H rows (512 B), index broadcast -----
__global__ void k_agg1(const u16* __restrict__ h1H, const int* __restrict__ off,
                       const int* __restrict__ eidx, u16* __restrict__ aggH) {
    int wid = (blockIdx.x * blockDim.x + threadIdx.x) >> 6;
    int lane = threadIdx.x & 63;
    if (wid >= N2v) return;
    int b = off[wid], e = off[wid + 1];
    float a0 = 0.f, a1 = 0.f, a2 = 0.f, a3 = 0.f;
    for (int base = b; base < e; base += 64) {
        int li = base + lane;
        int idx = eidx[li < e ? li : (e - 1)];
        int nch = e - base; if (nch > 64) nch = 64;
        for (int j = 0; j < nch; j++) {
            int s = __shfl(idx, j);
            const u16* row = &h1H[(size_t)s * 256];
            unsigned v0 = *(const unsigned*)&row[2 * lane];
            unsigned v1 = *(const unsigned*)&row[128 + 2 * lane];
            a0 += b2f((u16)v0); a1 += b2f((u16)(v0 >> 16));
            a2 += b2f((u16)v1); a3 += b2f((u16)(v1 >> 16));
        }
    }
    int deg = e - b;
    float inv = 1.0f / (float)(deg > 1 ? deg : 1);
    size_t rb = (size_t)wid * 256;
    *(unsigned*)&aggH[rb + 2 * lane] =
        (unsigned)f2b(a0 * inv) | ((unsigned)f2b(a1 * inv) << 16);
    *(unsigned*)&aggH[rb + 128 + 2 * lane] =
        (unsigned)f2b(a2 * inv) | ((unsigned)f2b(a3 * inv) << 16);
}

extern "C" void kernel_launch(void* const* d_in, const int* in_sizes, int n_in,
                              void* d_out, int out_size, void* d_ws, size_t ws_size,
                              hipStream_t stream) {
    const float* features = (const float*)d_in[0];
    const void* maskp     = d_in[1];
    const int* src0       = (const int*)d_in[2];
    const int* dst0       = (const int*)d_in[3];
    const int* src1       = (const int*)d_in[4];
    const int* dst1       = (const int*)d_in[5];
    const float* w_pin    = (const float*)d_in[7];
    const float* b_pin    = (const float*)d_in[8];
    const float* w_pout   = (const float*)d_in[9];
    const float* b_pout   = (const float*)d_in[10];
    const float* w_self0  = (const float*)d_in[11];
    const float* w_neigh0 = (const float*)d_in[12];
    const float* b0       = (const float*)d_in[13];
    const float* w_self1  = (const float*)d_in[14];
    const float* w_neigh1 = (const float*)d_in[15];
    const float* b1       = (const float*)d_in[16];
    const float* w_cls    = (const float*)d_in[17];
    const float* b_cls    = (const float*)d_in[18];
    float* out = (float*)d_out;
    (void)in_sizes; (void)n_in; (void)out_size; (void)ws_size;

    char* ws = (char*)d_ws;
    size_t o = 0;
    auto alloc = [&](size_t bytes) { size_t r = o; o += (bytes + 255) & ~(size_t)255; return r; };
    // zeroed block (one memset)
    size_t o_flag = alloc(4);
    size_t o_cnt0 = alloc(N1v * 4);
    size_t o_cur0 = alloc(N1v * 4);
    size_t o_cnt1 = alloc(N2v * 4);
    size_t o_cur1 = alloc(N2v * 4);
    size_t zero_end = o;
    // rest
    size_t o_G    = alloc((size_t)N0v * 192 * 2);   // 76.8 MB
    size_t o_aggH = alloc((size_t)N1v * 192 * 2);
    size_t o_h1H  = alloc((size_t)N1v * 256 * 2);
    size_t o_ag1H = alloc((size_t)N2v * 256 * 2);
    size_t o_wtph = alloc(128 * 128 * 2), o_wtpl = alloc(128 * 128 * 2);
    size_t o_wt0h = alloc(256 * 384 * 2), o_wt0l = alloc(256 * 384 * 2);
    size_t o_wt1h = alloc(256 * 512 * 2), o_wt1l = alloc(256 * 512 * 2);
    size_t o_off0 = alloc((N1v + 1) * 4);
    size_t o_off1 = alloc((N2v + 1) * 4);
    size_t o_ei0  = alloc((size_t)E0v * 4);
    size_t o_ei1  = alloc((size_t)E1v * 4);

    int* flag = (int*)(ws + o_flag);
    int* cnt0 = (int*)(ws + o_cnt0);
    int* cur0 = (int*)(ws + o_cur0);
    int* cnt1 = (int*)(ws + o_cnt1);
    int* cur1 = (int*)(ws + o_cur1);
    u16* G     = (u16*)(ws + o_G);
    u16* aggH  = (u16*)(ws + o_aggH);
    u16* h1H   = (u16*)(ws + o_h1H);
    u16* ag1H  = (u16*)(ws + o_ag1H);
    u16* WTph = (u16*)(ws + o_wtph);
    u16* WTpl = (u16*)(ws + o_wtpl);
    u16* WT0h = (u16*)(ws + o_wt0h);
    u16* WT0l = (u16*)(ws + o_wt0l);
    u16* WT1h = (u16*)(ws + o_wt1h);
    u16* WT1l = (u16*)(ws + o_wt1l);
    int* off0 = (int*)(ws + o_off0);
    int* off1 = (int*)(ws + o_off1);
    int* ei0  = (int*)(ws + o_ei0);
    int* ei1  = (int*)(ws + o_ei1);

    // 1: zero flag + counters in one memset
    hipMemsetAsync(ws + o_flag, 0, zero_end - o_flag, stream);

    // 2: prep (detect + weight splits + out = b_cls broadcast)
    k_prep<<<512, 256, 0, stream>>>((const unsigned*)maskp, flag,
                                    w_pin, w_pout, WTph, WTpl,
                                    w_self0, w_neigh0, WT0h, WT0l,
                                    w_self1, w_neigh1, WT1h, WT1l,
                                    b_cls, out);

    // 3-5: CSR for both graphs
    k_count2<<<1024, 256, 0, stream>>>(dst0, dst1, cnt0, cnt1);
    k_scan2<<<2, 1024, 0, stream>>>(cnt0, off0, cnt1, off1);
    k_scatter2<<<1024, 256, 0, stream>>>(src0, dst0, off0, cur0, ei0,
                                         src1, dst1, off1, cur1, ei1);

    // 6: prompt GEMM (LDS-free) -> G[N0,192] = [featH | psel]
    k_gemm_p<<<N0v / 64, 256, 0, stream>>>(features, WTph, WTpl,
                                           b_pin, b_pout, maskp, flag, G);

    // 7: layer-0 mean agg -> aggH[N1,192]
    k_agg0<<<(N1v + 3) / 4, 256, 0, stream>>>(G, off0, ei0, aggH);

    // 8: h1 = relu([G | agg] @ WT0 + b0) -> h1H[N1,256]   (K=384: 6+6 k-steps)
    k_dgemm<1, 12, 6><<<dim3((N1v + 63) / 64, 4), 256, 0, stream>>>(
        G, 192, aggH, 192, WT0h, WT0l, b0, h1H, nullptr, nullptr, N1v);

    // 9: layer-1 mean agg -> ag1H[N2,256]
    k_agg1<<<(N2v + 3) / 4, 256, 0, stream>>>(h1H, off1, ei1, ag1H);

    // 10: logits = ([h1|agg1] @ WT1 + b1) @ w_cls + b_cls  (fused, K=512)
    k_dgemm<3, 16, 8><<<dim3((N2v + 63) / 64, 4), 256, 0, stream>>>(
        h1H, 256, ag1H, 256, WT1h, WT1l, b1, nullptr, out, w_cls, N2v);
}

// Round 6
// 602.199 us; speedup vs baseline: 1.1041x; 1.1041x over previous
//
#include <hip/hip_runtime.h>

// ---------------------------------------------------------------------------
// GNNWithPrompt, f32 I/O. Hi-only bf16 activations, hi+lo bf16 weights.
// GEMMs: whole-K LDS A-tile in MFMA-frag-contiguous layout, ONE barrier,
// register-resident B in <=8-kstep chunks (<=64 VGPR live), unrolled MFMA
// stream. Classifier fused into layer-1 GEMM epilogue. 10 dispatches.
// ---------------------------------------------------------------------------

#define N0v 200000
#define N1v 50000
#define N2v 10000
#define E0v 800000
#define E1v 160000

using u16 = unsigned short;
typedef __attribute__((ext_vector_type(8))) short short8;
typedef __attribute__((ext_vector_type(4))) float f32x4;

__device__ __forceinline__ float b2f(u16 u) {
    union { unsigned int i; float f; } v; v.i = ((unsigned int)u) << 16; return v.f;
}
__device__ __forceinline__ u16 f2b(float f) {  // round-to-nearest-even
    union { float f; unsigned int i; } v; v.f = f;
    return (u16)((v.i + 0x7fffu + ((v.i >> 16) & 1u)) >> 16);
}
__device__ __forceinline__ void split2(float f, u16& h, u16& l) {
    h = f2b(f);
    l = f2b(f - b2f(h));
}

// --- prep: mask detect + weight hi/lo splits + out=bias init ---------------
__global__ void k_prep(const unsigned* mask, int* flag,
                       const float* w_pin, const float* w_pout, u16* WTph, u16* WTpl,
                       const float* ws0, const float* wn0, u16* WT0h, u16* WT0l,
                       const float* ws1, const float* wn1, u16* WT1h, u16* WT1l,
                       const float* bc, float* outp) {
    const int R0 = 50000;             // detect words
    const int R1 = R0 + 128 * 128;    // prompt WT
    const int R2 = R1 + 256 * 384;    // layer0 WT
    const int R3 = R2 + 256 * 512;    // layer1 WT
    const int R4 = R3 + 2 * N2v;      // out bias init
    for (int i = blockIdx.x * blockDim.x + threadIdx.x; i < R4;
         i += gridDim.x * blockDim.x) {
        if (i < R0) {
            if (mask[i] > 1u) atomicOr(flag, 1);
        } else if (i < R1) {
            int j = i - R0, n = j >> 7, k = j & 127;
            float f = (n < 64) ? w_pin[k * 64 + n] : w_pout[k * 64 + (n - 64)];
            split2(f, WTph[j], WTpl[j]);
        } else if (i < R2) {
            int j = i - R1, n = j / 384, k = j % 384;
            float f = (k < 192) ? ws0[k * 256 + n] : wn0[(k - 192) * 256 + n];
            split2(f, WT0h[j], WT0l[j]);
        } else if (i < R3) {
            int j = i - R2, n = j >> 9, k = j & 511;
            float f = (k < 256) ? ws1[k * 256 + n] : wn1[(k - 256) * 256 + n];
            split2(f, WT1h[j], WT1l[j]);
        } else {
            int j = i - R3;
            outp[j] = bc[j & 1];
        }
    }
}

// --- CSR build: both graphs per dispatch -----------------------------------
__global__ void k_count2(const int* __restrict__ dst0, const int* __restrict__ dst1,
                         int* cnt0, int* cnt1) {
    for (int i = blockIdx.x * blockDim.x + threadIdx.x; i < E0v + E1v;
         i += gridDim.x * blockDim.x) {
        if (i < E0v) atomicAdd(&cnt0[dst0[i]], 1);
        else         atomicAdd(&cnt1[dst1[i - E0v]], 1);
    }
}

__device__ void scan_body(const int* __restrict__ cnt, int* __restrict__ off, int n) {
    __shared__ int lds[1024];
    int t = threadIdx.x;
    int chunk = (n + 1023) >> 10;
    int b = t * chunk, e = b + chunk;
    if (e > n) e = n;
    int s = 0;
    for (int i = b; i < e; i++) s += cnt[i];
    lds[t] = s;
    __syncthreads();
    for (int d = 1; d < 1024; d <<= 1) {
        int v = (t >= d) ? lds[t - d] : 0;
        __syncthreads();
        lds[t] += v;
        __syncthreads();
    }
    int run = lds[t] - s;
    for (int i = b; i < e; i++) { off[i] = run; run += cnt[i]; }
    if (t == 1023) off[n] = lds[1023];
}

__global__ __launch_bounds__(1024) void k_scan2(const int* cnt0, int* off0,
                                                const int* cnt1, int* off1) {
    if (blockIdx.x == 0) scan_body(cnt0, off0, N1v);
    else                 scan_body(cnt1, off1, N2v);
}

__global__ void k_scatter2(const int* __restrict__ src0, const int* __restrict__ dst0,
                           const int* __restrict__ off0, int* cur0, int* ei0,
                           const int* __restrict__ src1, const int* __restrict__ dst1,
                           const int* __restrict__ off1, int* cur1, int* ei1) {
    for (int i = blockIdx.x * blockDim.x + threadIdx.x; i < E0v + E1v;
         i += gridDim.x * blockDim.x) {
        if (i < E0v) {
            int d = dst0[i];
            ei0[off0[d] + atomicAdd(&cur0[d], 1)] = src0[i];
        } else {
            int d = dst1[i - E0v];
            ei1[off1[d] + atomicAdd(&cur1[d], 1)] = src1[i - E0v];
        }
    }
}

// ---------------------------------------------------------------------------
// Prompt GEMM: 64 rows x 64 cols per block, grid 3125*2 (bn = bid&1).
// Whole-K (128) A staged once to LDS in frag-contiguous layout, ONE barrier.
// B (wave's 16 cols) in registers: 4 ksteps x 2 planes = 32 VGPR.
// bn==0 blocks side-store featH to G[:,0:128]; epilogue mask-select to
// G[:,128:192].
// ---------------------------------------------------------------------------
__global__ __launch_bounds__(256, 2) void k_gemm_p(
    const float* __restrict__ A, const u16* __restrict__ Bh, const u16* __restrict__ Bl,
    const float* __restrict__ b_pin, const float* __restrict__ b_pout,
    const void* maskp, const int* __restrict__ flag, u16* __restrict__ G) {
    __shared__ u16 LA[4 * 4 * 64 * 8];  // [mi][k0][lane][8] = 16 KB
    const int t = threadIdx.x;
    const int bm = blockIdx.x >> 1, bn = blockIdx.x & 1;
    const int lane = t & 63, w = t >> 6;
    const int m = lane & 15, q = lane >> 4;
    const int r0 = bm * 64;
    const int col = bn * 64 + w * 16 + m;

    // B frags (loop-invariant, 32 VGPRs)
    short8 bf[4][2];
#pragma unroll
    for (int k0 = 0; k0 < 4; k0++) {
        size_t b = (size_t)col * 128 + k0 * 32 + q * 8;
        bf[k0][0] = *(const short8*)&Bh[b];
        bf[k0][1] = *(const short8*)&Bl[b];
    }

    // stage A (f32 -> hi bf16) into frag-contiguous LDS; side-store featH
    {
        const int rr = t >> 2, k0 = t & 3;
        const int arow = r0 + rr;  // always < 200000 (3125*64 exact)
#pragma unroll
        for (int q2 = 0; q2 < 4; q2++) {
            const int c = k0 * 32 + q2 * 8;
            const float* ap = &A[(size_t)arow * 128 + c];
            float4 v0 = *(const float4*)ap, v1 = *(const float4*)(ap + 4);
            u16 h8[8];
            h8[0] = f2b(v0.x); h8[1] = f2b(v0.y); h8[2] = f2b(v0.z); h8[3] = f2b(v0.w);
            h8[4] = f2b(v1.x); h8[5] = f2b(v1.y); h8[6] = f2b(v1.z); h8[7] = f2b(v1.w);
            const int fl = ((rr >> 4) * 4 + k0) * 64 + (rr & 15) + 16 * q2;
            *(uint4*)&LA[fl * 8] = *(const uint4*)h8;
            if (bn == 0)
                *(uint4*)&G[(size_t)arow * 192 + c] = *(const uint4*)h8;
        }
    }
    __syncthreads();

    f32x4 acc[4] = {};
#pragma unroll
    for (int mi = 0; mi < 4; mi++) {
#pragma unroll
        for (int k0 = 0; k0 < 4; k0++) {
            short8 af = *(const short8*)&LA[(((mi * 4) + k0) * 64 + lane) * 8];
            acc[mi] = __builtin_amdgcn_mfma_f32_16x16x32_bf16(af, bf[k0][0], acc[mi], 0, 0, 0);
            acc[mi] = __builtin_amdgcn_mfma_f32_16x16x32_bf16(af, bf[k0][1], acc[mi], 0, 0, 0);
        }
    }

    const int fl = *flag;
    const float bv = (col < 64) ? b_pin[col] : b_pout[col - 64];
#pragma unroll
    for (int mi = 0; mi < 4; mi++) {
#pragma unroll
        for (int r = 0; r < 4; r++) {
            int row = r0 + mi * 16 + q * 4 + r;
            bool mk = fl ? (((const unsigned char*)maskp)[row] != 0)
                         : (((const int*)maskp)[row] != 0);
            if (mk == (col < 64)) {
                float v = acc[mi][r] + bv;
                v = v > 0.f ? v : 0.f;
                G[(size_t)row * 192 + 128 + (col & 63)] = f2b(v);
            }
        }
    }
}

// ---------------------------------------------------------------------------
// Direct GEMM: 64 rows x 64 cols/block, grid nbm*4 (bn = bid&3), N=256.
// Whole-K A-tile (2 segments, bf16) staged once, ONE barrier.
// B in register chunks of <=8 ksteps (<=64 VGPR live).
// MODE 1: relu -> bf16 CH.  MODE 3: fused classifier -> atomic out.
// ---------------------------------------------------------------------------
template <int MODE, int KT, int KE0>
__global__ __launch_bounds__(256, 2) void k_g(
    const u16* __restrict__ A0, int s0, const u16* __restrict__ A1, int s1,
    const u16* __restrict__ Bh, const u16* __restrict__ Bl,
    const float* __restrict__ bias,
    u16* __restrict__ CH, float* __restrict__ outp, const float* __restrict__ wc,
    int M) {
    __shared__ u16 LA[4 * KT * 64 * 8];  // KT*4 KB (48 KB / 64 KB)
    const int t = threadIdx.x;
    const int bm = blockIdx.x >> 2, bn = blockIdx.x & 3;
    const int lane = t & 63, w = t >> 6;
    const int m = lane & 15, q = lane >> 4;
    const int r0 = bm * 64;
    const int col = bn * 64 + w * 16 + m;
    const int K = KT * 32;

    // stage whole-K A-tile into frag-contiguous LDS
    {
        const int rr = t >> 2, quarter = t & 3;
        int arow = r0 + rr; if (arow >= M) arow = M - 1;
#pragma unroll
        for (int s = 0; s < KT / 4; s++) {
            const int kc = quarter * (KT / 4) + s;
#pragma unroll
            for (int q2 = 0; q2 < 4; q2++) {
                const int c = kc * 32 + q2 * 8;
                uint4 v = (c < KE0 * 32)
                              ? *(const uint4*)&A0[(size_t)arow * s0 + c]
                              : *(const uint4*)&A1[(size_t)arow * s1 + (c - KE0 * 32)];
                const int fl = ((rr >> 4) * KT + kc) * 64 + (rr & 15) + 16 * q2;
                *(uint4*)&LA[fl * 8] = v;
            }
        }
    }
    __syncthreads();

    f32x4 acc[4] = {};
#pragma unroll
    for (int kb = 0; kb < KT; kb += 8) {
        constexpr int KC8 = (KT < 8) ? KT : 8;
        const int KC = (KT - kb < KC8) ? (KT - kb) : KC8;
        short8 bf[KC8][2];
#pragma unroll
        for (int k0 = 0; k0 < KC8; k0++) {
            if (k0 < KC) {
                size_t b = (size_t)col * K + (kb + k0) * 32 + q * 8;
                bf[k0][0] = *(const short8*)&Bh[b];
                bf[k0][1] = *(const short8*)&Bl[b];
            }
        }
#pragma unroll
        for (int mi = 0; mi < 4; mi++) {
#pragma unroll
            for (int k0 = 0; k0 < KC8; k0++) {
                if (k0 < KC) {
                    short8 af = *(const short8*)&LA[((mi * KT + kb + k0) * 64 + lane) * 8];
                    acc[mi] = __builtin_amdgcn_mfma_f32_16x16x32_bf16(af, bf[k0][0], acc[mi], 0, 0, 0);
                    acc[mi] = __builtin_amdgcn_mfma_f32_16x16x32_bf16(af, bf[k0][1], acc[mi], 0, 0, 0);
                }
            }
        }
    }

    const float bv = bias[col];
    if (MODE == 1) {
#pragma unroll
        for (int mi = 0; mi < 4; mi++) {
#pragma unroll
            for (int r = 0; r < 4; r++) {
                int row = r0 + mi * 16 + q * 4 + r;
                if (row < M) {
                    float v = acc[mi][r] + bv;
                    v = v > 0.f ? v : 0.f;
                    CH[(size_t)row * 256 + col] = f2b(v);
                }
            }
        }
    } else {
        const float w0 = wc[col * 2], w1 = wc[col * 2 + 1];
#pragma unroll
        for (int mi = 0; mi < 4; mi++) {
#pragma unroll
            for (int r = 0; r < 4; r++) {
                int row = r0 + mi * 16 + q * 4 + r;
                float v = acc[mi][r] + bv;
                float p0 = v * w0, p1 = v * w1;
#pragma unroll
                for (int s = 1; s < 16; s <<= 1) {
                    p0 += __shfl_xor(p0, s);
                    p1 += __shfl_xor(p1, s);
                }
                if (m == 0 && row < M) {
                    atomicAdd(&outp[row * 2], p0);
                    atomicAdd(&outp[row * 2 + 1], p1);
                }
            }
        }
    }
}

// --- layer-0 mean-agg: wave/dst over G rows (384 B), index broadcast -------
__global__ void k_agg0(const u16* __restrict__ G, const int* __restrict__ off,
                       const int* __restrict__ eidx, u16* __restrict__ aggH) {
    int wid = (blockIdx.x * blockDim.x + threadIdx.x) >> 6;
    int lane = threadIdx.x & 63;
    if (wid >= N1v) return;
    int b = off[wid], e = off[wid + 1];
    float f0 = 0.f, f1 = 0.f, p0 = 0.f;
    for (int base = b; base < e; base += 64) {
        int li = base + lane;
        int idx = eidx[li < e ? li : (e - 1)];
        int nch = e - base; if (nch > 64) nch = 64;
        for (int j = 0; j < nch; j++) {
            int s = __shfl(idx, j);
            const u16* row = &G[(size_t)s * 192];
            unsigned fv = *(const unsigned*)&row[2 * lane];
            u16 pv = row[128 + lane];
            f0 += b2f((u16)fv);
            f1 += b2f((u16)(fv >> 16));
            p0 += b2f(pv);
        }
    }
    int deg = e - b;
    float inv = 1.0f / (float)(deg > 1 ? deg : 1);
    size_t rb = (size_t)wid * 192;
    *(unsigned*)&aggH[rb + 2 * lane] =
        (unsigned)f2b(f0 * inv) | ((unsigned)f2b(f1 * inv) << 16);
    aggH[rb + 128 + lane] = f2b(p0 * inv);
}

// --- layer-1 mean-agg: wave/dst over h1H rows (512 B), index broadcast -----
__global__ void k_agg1(const u16* __restrict__ h1H, const int* __restrict__ off,
                       const int* __restrict__ eidx, u16* __restrict__ aggH) {
    int wid = (blockIdx.x * blockDim.x + threadIdx.x) >> 6;
    int lane = threadIdx.x & 63;
    if (wid >= N2v) return;
    int b = off[wid], e = off[wid + 1];
    float a0 = 0.f, a1 = 0.f, a2 = 0.f, a3 = 0.f;
    for (int base = b; base < e; base += 64) {
        int li = base + lane;
        int idx = eidx[li < e ? li : (e - 1)];
        int nch = e - base; if (nch > 64) nch = 64;
        for (int j = 0; j < nch; j++) {
            int s = __shfl(idx, j);
            const u16* row = &h1H[(size_t)s * 256];
            unsigned v0 = *(const unsigned*)&row[2 * lane];
            unsigned v1 = *(const unsigned*)&row[128 + 2 * lane];
            a0 += b2f((u16)v0); a1 += b2f((u16)(v0 >> 16));
            a2 += b2f((u16)v1); a3 += b2f((u16)(v1 >> 16));
        }
    }
    int deg = e - b;
    float inv = 1.0f / (float)(deg > 1 ? deg : 1);
    size_t rb = (size_t)wid * 256;
    *(unsigned*)&aggH[rb + 2 * lane] =
        (unsigned)f2b(a0 * inv) | ((unsigned)f2b(a1 * inv) << 16);
    *(unsigned*)&aggH[rb + 128 + 2 * lane] =
        (unsigned)f2b(a2 * inv) | ((unsigned)f2b(a3 * inv) << 16);
}

extern "C" void kernel_launch(void* const* d_in, const int* in_sizes, int n_in,
                              void* d_out, int out_size, void* d_ws, size_t ws_size,
                              hipStream_t stream) {
    const float* features = (const float*)d_in[0];
    const void* maskp     = d_in[1];
    const int* src0       = (const int*)d_in[2];
    const int* dst0       = (const int*)d_in[3];
    const int* src1       = (const int*)d_in[4];
    const int* dst1       = (const int*)d_in[5];
    const float* w_pin    = (const float*)d_in[7];
    const float* b_pin    = (const float*)d_in[8];
    const float* w_pout   = (const float*)d_in[9];
    const float* b_pout   = (const float*)d_in[10];
    const float* w_self0  = (const float*)d_in[11];
    const float* w_neigh0 = (const float*)d_in[12];
    const float* b0       = (const float*)d_in[13];
    const float* w_self1  = (const float*)d_in[14];
    const float* w_neigh1 = (const float*)d_in[15];
    const float* b1       = (const float*)d_in[16];
    const float* w_cls    = (const float*)d_in[17];
    const float* b_cls    = (const float*)d_in[18];
    float* out = (float*)d_out;
    (void)in_sizes; (void)n_in; (void)out_size; (void)ws_size;

    char* ws = (char*)d_ws;
    size_t o = 0;
    auto alloc = [&](size_t bytes) { size_t r = o; o += (bytes + 255) & ~(size_t)255; return r; };
    // zeroed block (one memset)
    size_t o_flag = alloc(4);
    size_t o_cnt0 = alloc(N1v * 4);
    size_t o_cur0 = alloc(N1v * 4);
    size_t o_cnt1 = alloc(N2v * 4);
    size_t o_cur1 = alloc(N2v * 4);
    size_t zero_end = o;
    // rest
    size_t o_G    = alloc((size_t)N0v * 192 * 2);   // 76.8 MB
    size_t o_aggH = alloc((size_t)N1v * 192 * 2);
    size_t o_h1H  = alloc((size_t)N1v * 256 * 2);
    size_t o_ag1H = alloc((size_t)N2v * 256 * 2);
    size_t o_wtph = alloc(128 * 128 * 2), o_wtpl = alloc(128 * 128 * 2);
    size_t o_wt0h = alloc(256 * 384 * 2), o_wt0l = alloc(256 * 384 * 2);
    size_t o_wt1h = alloc(256 * 512 * 2), o_wt1l = alloc(256 * 512 * 2);
    size_t o_off0 = alloc((N1v + 1) * 4);
    size_t o_off1 = alloc((N2v + 1) * 4);
    size_t o_ei0  = alloc((size_t)E0v * 4);
    size_t o_ei1  = alloc((size_t)E1v * 4);

    int* flag = (int*)(ws + o_flag);
    int* cnt0 = (int*)(ws + o_cnt0);
    int* cur0 = (int*)(ws + o_cur0);
    int* cnt1 = (int*)(ws + o_cnt1);
    int* cur1 = (int*)(ws + o_cur1);
    u16* G     = (u16*)(ws + o_G);
    u16* aggH  = (u16*)(ws + o_aggH);
    u16* h1H   = (u16*)(ws + o_h1H);
    u16* ag1H  = (u16*)(ws + o_ag1H);
    u16* WTph = (u16*)(ws + o_wtph);
    u16* WTpl = (u16*)(ws + o_wtpl);
    u16* WT0h = (u16*)(ws + o_wt0h);
    u16* WT0l = (u16*)(ws + o_wt0l);
    u16* WT1h = (u16*)(ws + o_wt1h);
    u16* WT1l = (u16*)(ws + o_wt1l);
    int* off0 = (int*)(ws + o_off0);
    int* off1 = (int*)(ws + o_off1);
    int* ei0  = (int*)(ws + o_ei0);
    int* ei1  = (int*)(ws + o_ei1);

    // 1: zero flag + counters in one memset
    hipMemsetAsync(ws + o_flag, 0, zero_end - o_flag, stream);

    // 2: prep (detect + weight splits + out = b_cls broadcast)
    k_prep<<<512, 256, 0, stream>>>((const unsigned*)maskp, flag,
                                    w_pin, w_pout, WTph, WTpl,
                                    w_self0, w_neigh0, WT0h, WT0l,
                                    w_self1, w_neigh1, WT1h, WT1l,
                                    b_cls, out);

    // 3-5: CSR for both graphs
    k_count2<<<1024, 256, 0, stream>>>(dst0, dst1, cnt0, cnt1);
    k_scan2<<<2, 1024, 0, stream>>>(cnt0, off0, cnt1, off1);
    k_scatter2<<<1024, 256, 0, stream>>>(src0, dst0, off0, cur0, ei0,
                                         src1, dst1, off1, cur1, ei1);

    // 6: prompt GEMM -> G[N0,192] = [featH | psel]
    k_gemm_p<<<(N0v / 64) * 2, 256, 0, stream>>>(features, WTph, WTpl,
                                                 b_pin, b_pout, maskp, flag, G);

    // 7: layer-0 mean agg -> aggH[N1,192]
    k_agg0<<<(N1v + 3) / 4, 256, 0, stream>>>(G, off0, ei0, aggH);

    // 8: h1 = relu([G | agg] @ WT0 + b0) -> h1H[N1,256]   (K=384: 6+6 ksteps)
    k_g<1, 12, 6><<<((N1v + 63) / 64) * 4, 256, 0, stream>>>(
        G, 192, aggH, 192, WT0h, WT0l, b0, h1H, nullptr, nullptr, N1v);

    // 9: layer-1 mean agg -> ag1H[N2,256]
    k_agg1<<<(N2v + 3) / 4, 256, 0, stream>>>(h1H, off1, ei1, ag1H);

    // 10: logits = ([h1|agg1] @ WT1 + b1) @ w_cls + b_cls  (fused, K=512)
    k_g<3, 16, 8><<<((N2v + 63) / 64) * 4, 256, 0, stream>>>(
        h1H, 256, ag1H, 256, WT1h, WT1l, b1, nullptr, out, w_cls, N2v);
}

// Round 7
// 525.971 us; speedup vs baseline: 1.2641x; 1.1449x over previous
//
#include <hip/hip_runtime.h>

// ---------------------------------------------------------------------------
// GNNWithPrompt, f32 I/O. Hi-only bf16 activations, hi+lo bf16 weights.
// GEMMs: whole-K LDS A-tile (frag-contiguous, stride-68 swizzle = uniform
// banks), ONE barrier, register B chunks <=8 ksteps. ALL global stores are
// sector-full & coalesced (LDS-staged epilogues; contiguous featH store).
// Mean-agg uses index-broadcast + 4-edge manual pipelining. 9 dispatches.
// ---------------------------------------------------------------------------

#define N0v 200000
#define N1v 50000
#define N2v 10000
#define E0v 800000
#define E1v 160000

using u16 = unsigned short;
typedef __attribute__((ext_vector_type(8))) short short8;
typedef __attribute__((ext_vector_type(4))) float f32x4;

__device__ __forceinline__ float b2f(u16 u) {
    union { unsigned int i; float f; } v; v.i = ((unsigned int)u) << 16; return v.f;
}
__device__ __forceinline__ u16 f2b(float f) {  // round-to-nearest-even
    union { float f; unsigned int i; } v; v.f = f;
    return (u16)((v.i + 0x7fffu + ((v.i >> 16) & 1u)) >> 16);
}
__device__ __forceinline__ void split2(float f, u16& h, u16& l) {
    h = f2b(f);
    l = f2b(f - b2f(h));
}

// --- prep: detect + weight splits + out=bias init + BOTH degree counts -----
__global__ void k_prep(const unsigned* mask, int* flag,
                       const float* w_pin, const float* w_pout, u16* WTph, u16* WTpl,
                       const float* ws0, const float* wn0, u16* WT0h, u16* WT0l,
                       const float* ws1, const float* wn1, u16* WT1h, u16* WT1l,
                       const float* bc, float* outp,
                       const int* __restrict__ dst0, const int* __restrict__ dst1,
                       int* cnt0, int* cnt1) {
    const int R0 = 50000;             // detect words
    const int R1 = R0 + 128 * 128;    // prompt WT
    const int R2 = R1 + 256 * 384;    // layer0 WT
    const int R3 = R2 + 256 * 512;    // layer1 WT
    const int R4 = R3 + 2 * N2v;      // out bias init
    const int R5 = R4 + E0v;          // count graph 0
    const int R6 = R5 + E1v;          // count graph 1
    for (int i = blockIdx.x * blockDim.x + threadIdx.x; i < R6;
         i += gridDim.x * blockDim.x) {
        if (i < R0) {
            if (mask[i] > 1u) atomicOr(flag, 1);
        } else if (i < R1) {
            int j = i - R0, n = j >> 7, k = j & 127;
            float f = (n < 64) ? w_pin[k * 64 + n] : w_pout[k * 64 + (n - 64)];
            split2(f, WTph[j], WTpl[j]);
        } else if (i < R2) {
            int j = i - R1, n = j / 384, k = j % 384;
            float f = (k < 192) ? ws0[k * 256 + n] : wn0[(k - 192) * 256 + n];
            split2(f, WT0h[j], WT0l[j]);
        } else if (i < R3) {
            int j = i - R2, n = j >> 9, k = j & 511;
            float f = (k < 256) ? ws1[k * 256 + n] : wn1[(k - 256) * 256 + n];
            split2(f, WT1h[j], WT1l[j]);
        } else if (i < R4) {
            int j = i - R3;
            outp[j] = bc[j & 1];
        } else if (i < R5) {
            atomicAdd(&cnt0[dst0[i - R4]], 1);
        } else {
            atomicAdd(&cnt1[dst1[i - R5]], 1);
        }
    }
}

__device__ void scan_body(const int* __restrict__ cnt, int* __restrict__ off, int n) {
    __shared__ int lds[1024];
    int t = threadIdx.x;
    int chunk = (n + 1023) >> 10;
    int b = t * chunk, e = b + chunk;
    if (e > n) e = n;
    int s = 0;
    for (int i = b; i < e; i++) s += cnt[i];
    lds[t] = s;
    __syncthreads();
    for (int d = 1; d < 1024; d <<= 1) {
        int v = (t >= d) ? lds[t - d] : 0;
        __syncthreads();
        lds[t] += v;
        __syncthreads();
    }
    int run = lds[t] - s;
    for (int i = b; i < e; i++) { off[i] = run; run += cnt[i]; }
    if (t == 1023) off[n] = lds[1023];
}

__global__ __launch_bounds__(1024) void k_scan2(const int* cnt0, int* off0,
                                                const int* cnt1, int* off1) {
    if (blockIdx.x == 0) scan_body(cnt0, off0, N1v);
    else                 scan_body(cnt1, off1, N2v);
}

__global__ void k_scatter2(const int* __restrict__ src0, const int* __restrict__ dst0,
                           const int* __restrict__ off0, int* cur0, int* ei0,
                           const int* __restrict__ src1, const int* __restrict__ dst1,
                           const int* __restrict__ off1, int* cur1, int* ei1) {
    for (int i = blockIdx.x * blockDim.x + threadIdx.x; i < E0v + E1v;
         i += gridDim.x * blockDim.x) {
        if (i < E0v) {
            int d = dst0[i];
            ei0[off0[d] + atomicAdd(&cur0[d], 1)] = src0[i];
        } else {
            int d = dst1[i - E0v];
            ei1[off1[d] + atomicAdd(&cur1[d], 1)] = src1[i - E0v];
        }
    }
}

// ---------------------------------------------------------------------------
// Prompt GEMM: 64 rows x 64 cols/block, grid 3125*2 (bn=bid&1), K=128.
// Whole-K A in LDS (frag-contiguous, stride 68 groups), ONE barrier.
// bn==0 side-stores featH with per-instruction-contiguous 256B rows.
// Epilogue: psel tile staged in LDS -> one 128B line per row.
// ---------------------------------------------------------------------------
__global__ __launch_bounds__(256, 2) void k_gemm_p(
    const float* __restrict__ A, const u16* __restrict__ Bh, const u16* __restrict__ Bl,
    const float* __restrict__ b_pin, const float* __restrict__ b_pout,
    const void* maskp, const int* __restrict__ flag, u16* __restrict__ G) {
    __shared__ __align__(16) u16 LA[16 * 68 * 8];  // 16 frags, stride 68 -> 17.4 KB
    const int t = threadIdx.x;
    const int bm = blockIdx.x >> 1, bn = blockIdx.x & 1;
    const int lane = t & 63, w = t >> 6;
    const int m = lane & 15, q = lane >> 4;
    const int r0 = bm * 64;
    const int col = bn * 64 + w * 16 + m;

    // B frags (K=128: 4 ksteps x hi/lo = 32 VGPR)
    short8 bf[4][2];
#pragma unroll
    for (int k0 = 0; k0 < 4; k0++) {
        size_t b = (size_t)col * 128 + k0 * 32 + q * 8;
        bf[k0][0] = *(const short8*)&Bh[b];
        bf[k0][1] = *(const short8*)&Bl[b];
    }

    // stage A: thread handles (row = r0 + (t>>4) + 16p, chunk = t&15).
    // featH store: per instruction 4 rows x 256B fully contiguous (bn==0).
    {
        const int r15 = t >> 4, ch = t & 15;
        const int k0 = ch >> 2, q2 = ch & 3;
#pragma unroll
        for (int p = 0; p < 4; p++) {
            const int row = r0 + r15 + 16 * p;
            const float* ap = &A[(size_t)row * 128 + ch * 8];
            float4 v0 = *(const float4*)ap, v1 = *(const float4*)(ap + 4);
            u16 h8[8];
            h8[0] = f2b(v0.x); h8[1] = f2b(v0.y); h8[2] = f2b(v0.z); h8[3] = f2b(v0.w);
            h8[4] = f2b(v1.x); h8[5] = f2b(v1.y); h8[6] = f2b(v1.z); h8[7] = f2b(v1.w);
            if (bn == 0)
                *(uint4*)&G[(size_t)row * 192 + ch * 8] = *(const uint4*)h8;
            const int fi = p * 4 + k0, pos = 16 * q2 + r15;
            *(uint4*)&LA[(fi * 68 + pos) * 8] = *(const uint4*)h8;
        }
    }
    __syncthreads();

    f32x4 acc[4] = {};
#pragma unroll
    for (int mi = 0; mi < 4; mi++) {
#pragma unroll
        for (int k0 = 0; k0 < 4; k0++) {
            short8 af = *(const short8*)&LA[((mi * 4 + k0) * 68 + lane) * 8];
            acc[mi] = __builtin_amdgcn_mfma_f32_16x16x32_bf16(af, bf[k0][0], acc[mi], 0, 0, 0);
            acc[mi] = __builtin_amdgcn_mfma_f32_16x16x32_bf16(af, bf[k0][1], acc[mi], 0, 0, 0);
        }
    }

    // epilogue: stage relu(acc+bias) tile (64x64 u16, stride 72) in LDS
    const float bv = (col < 64) ? b_pin[col] : b_pout[col - 64];
    __syncthreads();  // all frag reads done; reuse LA
#pragma unroll
    for (int mi = 0; mi < 4; mi++) {
#pragma unroll
        for (int r = 0; r < 4; r++) {
            float v = acc[mi][r] + bv;
            v = v > 0.f ? v : 0.f;
            LA[(mi * 16 + q * 4 + r) * 72 + w * 16 + m] = f2b(v);
        }
    }
    __syncthreads();
    // write: one full 128B line per selected row (8 threads x 16B)
    const int fl = *flag;
    {
        const int c8 = t & 7;
#pragma unroll
        for (int pass = 0; pass < 2; pass++) {
            const int rt = pass * 32 + (t >> 3);
            const int row = r0 + rt;
            bool mk = fl ? (((const unsigned char*)maskp)[row] != 0)
                         : (((const int*)maskp)[row] != 0);
            if (mk == (bn == 0)) {
                *(uint4*)&G[(size_t)row * 192 + 128 + c8 * 8] =
                    *(const uint4*)&LA[rt * 72 + c8 * 8];
            }
        }
    }
}

// ---------------------------------------------------------------------------
// Direct GEMM: MT rows x 64 cols/block, grid nbm*4 (bn=bid&3), N-out=256.
// Whole-K A (2 bf16 segments) in LDS once, ONE barrier, B in <=8-kstep
// register chunks. MODE 1: relu -> bf16 CH via LDS-staged 128B/row writes.
// MODE 3: fused classifier -> atomic out.
// ---------------------------------------------------------------------------
template <int MODE, int KT, int KE0, int MT>
__global__ __launch_bounds__(256, 2) void k_g(
    const u16* __restrict__ A0, int s0, const u16* __restrict__ A1, int s1,
    const u16* __restrict__ Bh, const u16* __restrict__ Bl,
    const float* __restrict__ bias,
    u16* __restrict__ CH, float* __restrict__ outp, const float* __restrict__ wc,
    int M) {
    constexpr int MI = MT / 16;
    __shared__ __align__(16) u16 LA[MI * KT * 68 * 8];
    const int t = threadIdx.x;
    const int bm = blockIdx.x >> 2, bn = blockIdx.x & 3;
    const int lane = t & 63, w = t >> 6;
    const int m = lane & 15, q = lane >> 4;
    const int r0 = bm * MT;
    const int col = bn * 64 + w * 16 + m;
    const int K = KT * 32;

    // stage whole-K A-tile (reads; 64B-contiguous per thread)
    {
        constexpr int TPR = 256 / MT;      // threads per row (4 or 8)
        constexpr int SPT = KT / TPR;      // ksteps per thread (3 or 2)
        const int rr = t / TPR, sub = t & (TPR - 1);
        int arow = r0 + rr; if (arow >= M) arow = M - 1;
        const int mi = rr >> 4, r15 = rr & 15;
#pragma unroll
        for (int s = 0; s < SPT; s++) {
            const int kc = sub * SPT + s;
#pragma unroll
            for (int q2 = 0; q2 < 4; q2++) {
                const int c = kc * 32 + q2 * 8;
                uint4 v = (c < KE0 * 32)
                              ? *(const uint4*)&A0[(size_t)arow * s0 + c]
                              : *(const uint4*)&A1[(size_t)arow * s1 + (c - KE0 * 32)];
                *(uint4*)&LA[((mi * KT + kc) * 68 + 16 * q2 + r15) * 8] = v;
            }
        }
    }
    __syncthreads();

    f32x4 acc[MI] = {};
#pragma unroll
    for (int kb = 0; kb < KT; kb += 8) {
        constexpr int KC8 = (KT < 8) ? KT : 8;
        const int KC = (KT - kb < KC8) ? (KT - kb) : KC8;
        short8 bf[KC8][2];
#pragma unroll
        for (int k0 = 0; k0 < KC8; k0++) {
            if (k0 < KC) {
                size_t b = (size_t)col * K + (kb + k0) * 32 + q * 8;
                bf[k0][0] = *(const short8*)&Bh[b];
                bf[k0][1] = *(const short8*)&Bl[b];
            }
        }
#pragma unroll
        for (int mi = 0; mi < MI; mi++) {
#pragma unroll
            for (int k0 = 0; k0 < KC8; k0++) {
                if (k0 < KC) {
                    short8 af = *(const short8*)&LA[((mi * KT + kb + k0) * 68 + lane) * 8];
                    acc[mi] = __builtin_amdgcn_mfma_f32_16x16x32_bf16(af, bf[k0][0], acc[mi], 0, 0, 0);
                    acc[mi] = __builtin_amdgcn_mfma_f32_16x16x32_bf16(af, bf[k0][1], acc[mi], 0, 0, 0);
                }
            }
        }
    }

    const float bv = bias[col];
    if (MODE == 1) {
        // stage tile (MT x 64 u16, stride 72) then 128B-per-row writes
        __syncthreads();
#pragma unroll
        for (int mi = 0; mi < MI; mi++) {
#pragma unroll
            for (int r = 0; r < 4; r++) {
                float v = acc[mi][r] + bv;
                v = v > 0.f ? v : 0.f;
                LA[(mi * 16 + q * 4 + r) * 72 + w * 16 + m] = f2b(v);
            }
        }
        __syncthreads();
        const int c8 = t & 7;
#pragma unroll
        for (int pass = 0; pass < MT / 32; pass++) {
            const int rt = pass * 32 + (t >> 3);
            const int row = r0 + rt;
            if (row < M) {
                *(uint4*)&CH[(size_t)row * 256 + bn * 64 + c8 * 8] =
                    *(const uint4*)&LA[rt * 72 + c8 * 8];
            }
        }
    } else {
        const float w0 = wc[col * 2], w1 = wc[col * 2 + 1];
#pragma unroll
        for (int mi = 0; mi < MI; mi++) {
#pragma unroll
            for (int r = 0; r < 4; r++) {
                int row = r0 + mi * 16 + q * 4 + r;
                float v = acc[mi][r] + bv;
                float p0 = v * w0, p1 = v * w1;
#pragma unroll
                for (int s = 1; s < 16; s <<= 1) {
                    p0 += __shfl_xor(p0, s);
                    p1 += __shfl_xor(p1, s);
                }
                if (m == 0 && row < M) {
                    atomicAdd(&outp[row * 2], p0);
                    atomicAdd(&outp[row * 2 + 1], p1);
                }
            }
        }
    }
}

// --- layer-0 mean-agg: wave/dst over G rows (384B), 4-edge pipelined -------
__global__ void k_agg0(const u16* __restrict__ G, const int* __restrict__ off,
                       const int* __restrict__ eidx, u16* __restrict__ aggH) {
    int wid = (blockIdx.x * blockDim.x + threadIdx.x) >> 6;
    int lane = threadIdx.x & 63;
    if (wid >= N1v) return;
    int b = off[wid], e = off[wid + 1];
    float f0 = 0.f, f1 = 0.f, p0 = 0.f;
    for (int base = b; base < e; base += 64) {
        int li = base + lane;
        int idx = eidx[li < e ? li : (e - 1)];
        int nch = e - base; if (nch > 64) nch = 64;
        int j = 0;
        for (; j + 4 <= nch; j += 4) {
            int sa = __shfl(idx, j), sb = __shfl(idx, j + 1);
            int sc = __shfl(idx, j + 2), sd = __shfl(idx, j + 3);
            const u16* ra = &G[(size_t)sa * 192];
            const u16* rb = &G[(size_t)sb * 192];
            const u16* rc = &G[(size_t)sc * 192];
            const u16* rd = &G[(size_t)sd * 192];
            unsigned fa = *(const unsigned*)&ra[2 * lane];
            unsigned fb = *(const unsigned*)&rb[2 * lane];
            unsigned fc = *(const unsigned*)&rc[2 * lane];
            unsigned fd = *(const unsigned*)&rd[2 * lane];
            u16 pa = ra[128 + lane], pb = rb[128 + lane];
            u16 pc = rc[128 + lane], pd = rd[128 + lane];
            f0 += b2f((u16)fa) + b2f((u16)fb) + b2f((u16)fc) + b2f((u16)fd);
            f1 += b2f((u16)(fa >> 16)) + b2f((u16)(fb >> 16)) +
                  b2f((u16)(fc >> 16)) + b2f((u16)(fd >> 16));
            p0 += b2f(pa) + b2f(pb) + b2f(pc) + b2f(pd);
        }
        for (; j < nch; j++) {
            int s = __shfl(idx, j);
            const u16* row = &G[(size_t)s * 192];
            unsigned fv = *(const unsigned*)&row[2 * lane];
            f0 += b2f((u16)fv);
            f1 += b2f((u16)(fv >> 16));
            p0 += b2f(row[128 + lane]);
        }
    }
    int deg = e - b;
    float inv = 1.0f / (float)(deg > 1 ? deg : 1);
    size_t rb2 = (size_t)wid * 192;
    *(unsigned*)&aggH[rb2 + 2 * lane] =
        (unsigned)f2b(f0 * inv) | ((unsigned)f2b(f1 * inv) << 16);
    aggH[rb2 + 128 + lane] = f2b(p0 * inv);
}

// --- layer-1 mean-agg: wave/dst over h1H rows (512B), 4-edge pipelined -----
__global__ void k_agg1(const u16* __restrict__ h1H, const int* __restrict__ off,
                       const int* __restrict__ eidx, u16* __restrict__ aggH) {
    int wid = (blockIdx.x * blockDim.x + threadIdx.x) >> 6;
    int lane = threadIdx.x & 63;
    if (wid >= N2v) return;
    int b = off[wid], e = off[wid + 1];
    float a0 = 0.f, a1 = 0.f, a2 = 0.f, a3 = 0.f;
    for (int base = b; base < e; base += 64) {
        int li = base + lane;
        int idx = eidx[li < e ? li : (e - 1)];
        int nch = e - base; if (nch > 64) nch = 64;
        int j = 0;
        for (; j + 4 <= nch; j += 4) {
            int sa = __shfl(idx, j), sb = __shfl(idx, j + 1);
            int sc = __shfl(idx, j + 2), sd = __shfl(idx, j + 3);
            const u16* ra = &h1H[(size_t)sa * 256];
            const u16* rb = &h1H[(size_t)sb * 256];
            const u16* rc = &h1H[(size_t)sc * 256];
            const u16* rd = &h1H[(size_t)sd * 256];
            unsigned va0 = *(const unsigned*)&ra[2 * lane];
            unsigned vb0 = *(const unsigned*)&rb[2 * lane];
            unsigned vc0 = *(const unsigned*)&rc[2 * lane];
            unsigned vd0 = *(const unsigned*)&rd[2 * lane];
            unsigned va1 = *(const unsigned*)&ra[128 + 2 * lane];
            unsigned vb1 = *(const unsigned*)&rb[128 + 2 * lane];
            unsigned vc1 = *(const unsigned*)&rc[128 + 2 * lane];
            unsigned vd1 = *(const unsigned*)&rd[128 + 2 * lane];
            a0 += b2f((u16)va0) + b2f((u16)vb0) + b2f((u16)vc0) + b2f((u16)vd0);
            a1 += b2f((u16)(va0 >> 16)) + b2f((u16)(vb0 >> 16)) +
                  b2f((u16)(vc0 >> 16)) + b2f((u16)(vd0 >> 16));
            a2 += b2f((u16)va1) + b2f((u16)vb1) + b2f((u16)vc1) + b2f((u16)vd1);
            a3 += b2f((u16)(va1 >> 16)) + b2f((u16)(vb1 >> 16)) +
                  b2f((u16)(vc1 >> 16)) + b2f((u16)(vd1 >> 16));
        }
        for (; j < nch; j++) {
            int s = __shfl(idx, j);
            const u16* row = &h1H[(size_t)s * 256];
            unsigned v0 = *(const unsigned*)&row[2 * lane];
            unsigned v1 = *(const unsigned*)&row[128 + 2 * lane];
            a0 += b2f((u16)v0); a1 += b2f((u16)(v0 >> 16));
            a2 += b2f((u16)v1); a3 += b2f((u16)(v1 >> 16));
        }
    }
    int deg = e - b;
    float inv = 1.0f / (float)(deg > 1 ? deg : 1);
    size_t rb2 = (size_t)wid * 256;
    *(unsigned*)&aggH[rb2 + 2 * lane] =
        (unsigned)f2b(a0 * inv) | ((unsigned)f2b(a1 * inv) << 16);
    *(unsigned*)&aggH[rb2 + 128 + 2 * lane] =
        (unsigned)f2b(a2 * inv) | ((unsigned)f2b(a3 * inv) << 16);
}

extern "C" void kernel_launch(void* const* d_in, const int* in_sizes, int n_in,
                              void* d_out, int out_size, void* d_ws, size_t ws_size,
                              hipStream_t stream) {
    const float* features = (const float*)d_in[0];
    const void* maskp     = d_in[1];
    const int* src0       = (const int*)d_in[2];
    const int* dst0       = (const int*)d_in[3];
    const int* src1       = (const int*)d_in[4];
    const int* dst1       = (const int*)d_in[5];
    const float* w_pin    = (const float*)d_in[7];
    const float* b_pin    = (const float*)d_in[8];
    const float* w_pout   = (const float*)d_in[9];
    const float* b_pout   = (const float*)d_in[10];
    const float* w_self0  = (const float*)d_in[11];
    const float* w_neigh0 = (const float*)d_in[12];
    const float* b0       = (const float*)d_in[13];
    const float* w_self1  = (const float*)d_in[14];
    const float* w_neigh1 = (const float*)d_in[15];
    const float* b1       = (const float*)d_in[16];
    const float* w_cls    = (const float*)d_in[17];
    const float* b_cls    = (const float*)d_in[18];
    float* out = (float*)d_out;
    (void)in_sizes; (void)n_in; (void)out_size; (void)ws_size;

    char* ws = (char*)d_ws;
    size_t o = 0;
    auto alloc = [&](size_t bytes) { size_t r = o; o += (bytes + 255) & ~(size_t)255; return r; };
    // zeroed block (one memset)
    size_t o_flag = alloc(4);
    size_t o_cnt0 = alloc(N1v * 4);
    size_t o_cur0 = alloc(N1v * 4);
    size_t o_cnt1 = alloc(N2v * 4);
    size_t o_cur1 = alloc(N2v * 4);
    size_t zero_end = o;
    // rest
    size_t o_G    = alloc((size_t)N0v * 192 * 2);   // 76.8 MB
    size_t o_aggH = alloc((size_t)N1v * 192 * 2);
    size_t o_h1H  = alloc((size_t)N1v * 256 * 2);
    size_t o_ag1H = alloc((size_t)N2v * 256 * 2);
    size_t o_wtph = alloc(128 * 128 * 2), o_wtpl = alloc(128 * 128 * 2);
    size_t o_wt0h = alloc(256 * 384 * 2), o_wt0l = alloc(256 * 384 * 2);
    size_t o_wt1h = alloc(256 * 512 * 2), o_wt1l = alloc(256 * 512 * 2);
    size_t o_off0 = alloc((N1v + 1) * 4);
    size_t o_off1 = alloc((N2v + 1) * 4);
    size_t o_ei0  = alloc((size_t)E0v * 4);
    size_t o_ei1  = alloc((size_t)E1v * 4);

    int* flag = (int*)(ws + o_flag);
    int* cnt0 = (int*)(ws + o_cnt0);
    int* cur0 = (int*)(ws + o_cur0);
    int* cnt1 = (int*)(ws + o_cnt1);
    int* cur1 = (int*)(ws + o_cur1);
    u16* G     = (u16*)(ws + o_G);
    u16* aggH  = (u16*)(ws + o_aggH);
    u16* h1H   = (u16*)(ws + o_h1H);
    u16* ag1H  = (u16*)(ws + o_ag1H);
    u16* WTph = (u16*)(ws + o_wtph);
    u16* WTpl = (u16*)(ws + o_wtpl);
    u16* WT0h = (u16*)(ws + o_wt0h);
    u16* WT0l = (u16*)(ws + o_wt0l);
    u16* WT1h = (u16*)(ws + o_wt1h);
    u16* WT1l = (u16*)(ws + o_wt1l);
    int* off0 = (int*)(ws + o_off0);
    int* off1 = (int*)(ws + o_off1);
    int* ei0  = (int*)(ws + o_ei0);
    int* ei1  = (int*)(ws + o_ei1);

    // 1: zero flag + counters in one memset
    hipMemsetAsync(ws + o_flag, 0, zero_end - o_flag, stream);

    // 2: prep (detect + weight splits + out init + degree counts)
    k_prep<<<1024, 256, 0, stream>>>((const unsigned*)maskp, flag,
                                     w_pin, w_pout, WTph, WTpl,
                                     w_self0, w_neigh0, WT0h, WT0l,
                                     w_self1, w_neigh1, WT1h, WT1l,
                                     b_cls, out, dst0, dst1, cnt0, cnt1);

    // 3-4: CSR offsets + edge scatter
    k_scan2<<<2, 1024, 0, stream>>>(cnt0, off0, cnt1, off1);
    k_scatter2<<<1024, 256, 0, stream>>>(src0, dst0, off0, cur0, ei0,
                                         src1, dst1, off1, cur1, ei1);

    // 5: prompt GEMM -> G[N0,192] = [featH | psel]
    k_gemm_p<<<(N0v / 64) * 2, 256, 0, stream>>>(features, WTph, WTpl,
                                                 b_pin, b_pout, maskp, flag, G);

    // 6: layer-0 mean agg -> aggH[N1,192]
    k_agg0<<<(N1v + 3) / 4, 256, 0, stream>>>(G, off0, ei0, aggH);

    // 7: h1 = relu([G | agg] @ WT0 + b0) -> h1H[N1,256]  (K=384: 6+6 ksteps)
    k_g<1, 12, 6, 64><<<((N1v + 63) / 64) * 4, 256, 0, stream>>>(
        G, 192, aggH, 192, WT0h, WT0l, b0, h1H, nullptr, nullptr, N1v);

    // 8: layer-1 mean agg -> ag1H[N2,256]
    k_agg1<<<(N2v + 3) / 4, 256, 0, stream>>>(h1H, off1, ei1, ag1H);

    // 9: logits = ([h1|agg1] @ WT1 + b1) @ w_cls + b_cls  (fused, K=512)
    k_g<3, 16, 8, 32><<<((N2v + 31) / 32) * 4, 256, 0, stream>>>(
        h1H, 256, ag1H, 256, WT1h, WT1l, b1, nullptr, out, w_cls, N2v);
}

// Round 8
// 453.235 us; speedup vs baseline: 1.4670x; 1.1605x over previous
//
#include <hip/hip_runtime.h>

// ---------------------------------------------------------------------------
// GNNWithPrompt, f32 I/O. Hi-only bf16 activations, hi+lo bf16 weights.
// GEMMs: whole-K LDS A-tile (frag-contiguous, stride-68 swizzle), ONE
// barrier, register B chunks <=8 ksteps, sector-full coalesced stores.
// CSR: hierarchical 2-kernel scan (59-way parallel) replaces 2-block scan.
// Mean-agg: index-broadcast + 4-edge pipelining. 10 dispatches.
// ---------------------------------------------------------------------------

#define N0v 200000
#define N1v 50000
#define N2v 10000
#define E0v 800000
#define E1v 160000
#define TB0 49            // graph0 scan tiles (1024 each)
#define TB1 10            // graph1 scan tiles
#define TBL (TB0 + TB1)

using u16 = unsigned short;
typedef __attribute__((ext_vector_type(8))) short short8;
typedef __attribute__((ext_vector_type(4))) float f32x4;

__device__ __forceinline__ float b2f(u16 u) {
    union { unsigned int i; float f; } v; v.i = ((unsigned int)u) << 16; return v.f;
}
__device__ __forceinline__ u16 f2b(float f) {  // round-to-nearest-even
    union { float f; unsigned int i; } v; v.f = f;
    return (u16)((v.i + 0x7fffu + ((v.i >> 16) & 1u)) >> 16);
}
__device__ __forceinline__ void split2(float f, u16& h, u16& l) {
    h = f2b(f);
    l = f2b(f - b2f(h));
}

// --- prep: detect + weight splits + out=bias init + BOTH degree counts -----
__global__ void k_prep(const unsigned* mask, int* flag,
                       const float* w_pin, const float* w_pout, u16* WTph, u16* WTpl,
                       const float* ws0, const float* wn0, u16* WT0h, u16* WT0l,
                       const float* ws1, const float* wn1, u16* WT1h, u16* WT1l,
                       const float* bc, float* outp,
                       const int* __restrict__ dst0, const int* __restrict__ dst1,
                       int* cnt0, int* cnt1) {
    const int R0 = 50000;             // detect words
    const int R1 = R0 + 128 * 128;    // prompt WT
    const int R2 = R1 + 256 * 384;    // layer0 WT
    const int R3 = R2 + 256 * 512;    // layer1 WT
    const int R4 = R3 + 2 * N2v;      // out bias init
    const int R5 = R4 + E0v;          // count graph 0
    const int R6 = R5 + E1v;          // count graph 1
    for (int i = blockIdx.x * blockDim.x + threadIdx.x; i < R6;
         i += gridDim.x * blockDim.x) {
        if (i < R0) {
            if (mask[i] > 1u) atomicOr(flag, 1);
        } else if (i < R1) {
            int j = i - R0, n = j >> 7, k = j & 127;
            float f = (n < 64) ? w_pin[k * 64 + n] : w_pout[k * 64 + (n - 64)];
            split2(f, WTph[j], WTpl[j]);
        } else if (i < R2) {
            int j = i - R1, n = j / 384, k = j % 384;
            float f = (k < 192) ? ws0[k * 256 + n] : wn0[(k - 192) * 256 + n];
            split2(f, WT0h[j], WT0l[j]);
        } else if (i < R3) {
            int j = i - R2, n = j >> 9, k = j & 511;
            float f = (k < 256) ? ws1[k * 256 + n] : wn1[(k - 256) * 256 + n];
            split2(f, WT1h[j], WT1l[j]);
        } else if (i < R4) {
            int j = i - R3;
            outp[j] = bc[j & 1];
        } else if (i < R5) {
            atomicAdd(&cnt0[dst0[i - R4]], 1);
        } else {
            atomicAdd(&cnt1[dst1[i - R5]], 1);
        }
    }
}

// --- hierarchical scan, pass A: per-tile local exclusive scan + tile sums --
__global__ __launch_bounds__(256) void k_scan_a(const int* __restrict__ cnt0,
                                                int* __restrict__ off0,
                                                const int* __restrict__ cnt1,
                                                int* __restrict__ off1,
                                                int* __restrict__ tsum) {
    __shared__ int sd[256];
    const int t = threadIdx.x;
    const int blk = blockIdx.x;
    const int g1 = (blk >= TB0);
    const int b = g1 ? blk - TB0 : blk;
    const int n = g1 ? N2v : N1v;
    const int* cnt = g1 ? cnt1 : cnt0;
    int* off = g1 ? off1 : off0;
    const int i0 = b * 1024 + t * 4;
    int c[4] = {0, 0, 0, 0};
    if (i0 + 3 < n) {
        *(int4*)c = *(const int4*)&cnt[i0];
    } else {
        for (int j = 0; j < 4; j++) if (i0 + j < n) c[j] = cnt[i0 + j];
    }
    int s = c[0] + c[1] + c[2] + c[3];
    sd[t] = s;
    __syncthreads();
#pragma unroll
    for (int d = 1; d < 256; d <<= 1) {
        int v = (t >= d) ? sd[t - d] : 0;
        __syncthreads();
        sd[t] += v;
        __syncthreads();
    }
    int run = sd[t] - s;  // exclusive prefix within tile
    int o4[4];
#pragma unroll
    for (int j = 0; j < 4; j++) { o4[j] = run; run += c[j]; }
    if (i0 + 3 < n) *(int4*)&off[i0] = *(const int4*)o4;
    else for (int j = 0; j < 4; j++) if (i0 + j < n) off[i0 + j] = o4[j];
    if (t == 255) tsum[blk] = sd[255];
}

// --- hierarchical scan, pass C: add tile bases (segmented), sentinels ------
__global__ __launch_bounds__(256) void k_scan_c(int* __restrict__ off0,
                                                int* __restrict__ off1,
                                                const int* __restrict__ tsum) {
    __shared__ int lbase;
    const int t = threadIdx.x;
    const int blk = blockIdx.x;
    const int g1 = (blk >= TB0);
    const int b = g1 ? blk - TB0 : blk;
    const int n = g1 ? N2v : N1v;
    int* off = g1 ? off1 : off0;
    if (t < 64) {
        int v = (t < TBL) ? tsum[t] : 0;
        int incl = v;
#pragma unroll
        for (int d = 1; d < 64; d <<= 1) {
            int u = __shfl_up(incl, d);
            if (t >= d) incl += u;
        }
        int total0 = __shfl(incl, TB0 - 1);      // sum of graph-0 tiles
        if (t == blk) lbase = (incl - v) - (g1 ? total0 : 0);
    }
    __syncthreads();
    const int base = lbase;
    const int i0 = b * 1024 + t * 4;
    if (i0 + 3 < n) {
        int4 v = *(int4*)&off[i0];
        v.x += base; v.y += base; v.z += base; v.w += base;
        *(int4*)&off[i0] = v;
    } else {
        for (int j = 0; j < 4; j++) if (i0 + j < n) off[i0 + j] += base;
    }
    if (blk == 0 && t == 0) { off0[N1v] = E0v; off1[N2v] = E1v; }
}

__global__ void k_scatter2(const int* __restrict__ src0, const int* __restrict__ dst0,
                           const int* __restrict__ off0, int* cur0, int* ei0,
                           const int* __restrict__ src1, const int* __restrict__ dst1,
                           const int* __restrict__ off1, int* cur1, int* ei1) {
    for (int i = blockIdx.x * blockDim.x + threadIdx.x; i < E0v + E1v;
         i += gridDim.x * blockDim.x) {
        if (i < E0v) {
            int d = dst0[i];
            ei0[off0[d] + atomicAdd(&cur0[d], 1)] = src0[i];
        } else {
            int d = dst1[i - E0v];
            ei1[off1[d] + atomicAdd(&cur1[d], 1)] = src1[i - E0v];
        }
    }
}

// ---------------------------------------------------------------------------
// Prompt GEMM: 64 rows x 64 cols/block, grid 3125*2 (bn=bid&1), K=128.
// Whole-K A in LDS (frag-contiguous, stride 68 groups), ONE barrier.
// bn==0 side-stores featH with per-instruction-contiguous 256B rows.
// Epilogue: psel tile staged in LDS -> one 128B line per row.
// ---------------------------------------------------------------------------
__global__ __launch_bounds__(256, 2) void k_gemm_p(
    const float* __restrict__ A, const u16* __restrict__ Bh, const u16* __restrict__ Bl,
    const float* __restrict__ b_pin, const float* __restrict__ b_pout,
    const void* maskp, const int* __restrict__ flag, u16* __restrict__ G) {
    __shared__ __align__(16) u16 LA[16 * 68 * 8];  // 16 frags, stride 68 -> 17.4 KB
    const int t = threadIdx.x;
    const int bm = blockIdx.x >> 1, bn = blockIdx.x & 1;
    const int lane = t & 63, w = t >> 6;
    const int m = lane & 15, q = lane >> 4;
    const int r0 = bm * 64;
    const int col = bn * 64 + w * 16 + m;

    short8 bf[4][2];
#pragma unroll
    for (int k0 = 0; k0 < 4; k0++) {
        size_t b = (size_t)col * 128 + k0 * 32 + q * 8;
        bf[k0][0] = *(const short8*)&Bh[b];
        bf[k0][1] = *(const short8*)&Bl[b];
    }

    {
        const int r15 = t >> 4, ch = t & 15;
        const int k0 = ch >> 2, q2 = ch & 3;
#pragma unroll
        for (int p = 0; p < 4; p++) {
            const int row = r0 + r15 + 16 * p;
            const float* ap = &A[(size_t)row * 128 + ch * 8];
            float4 v0 = *(const float4*)ap, v1 = *(const float4*)(ap + 4);
            u16 h8[8];
            h8[0] = f2b(v0.x); h8[1] = f2b(v0.y); h8[2] = f2b(v0.z); h8[3] = f2b(v0.w);
            h8[4] = f2b(v1.x); h8[5] = f2b(v1.y); h8[6] = f2b(v1.z); h8[7] = f2b(v1.w);
            if (bn == 0)
                *(uint4*)&G[(size_t)row * 192 + ch * 8] = *(const uint4*)h8;
            const int fi = p * 4 + k0, pos = 16 * q2 + r15;
            *(uint4*)&LA[(fi * 68 + pos) * 8] = *(const uint4*)h8;
        }
    }
    __syncthreads();

    f32x4 acc[4] = {};
#pragma unroll
    for (int mi = 0; mi < 4; mi++) {
#pragma unroll
        for (int k0 = 0; k0 < 4; k0++) {
            short8 af = *(const short8*)&LA[((mi * 4 + k0) * 68 + lane) * 8];
            acc[mi] = __builtin_amdgcn_mfma_f32_16x16x32_bf16(af, bf[k0][0], acc[mi], 0, 0, 0);
            acc[mi] = __builtin_amdgcn_mfma_f32_16x16x32_bf16(af, bf[k0][1], acc[mi], 0, 0, 0);
        }
    }

    const float bv = (col < 64) ? b_pin[col] : b_pout[col - 64];
    __syncthreads();  // all frag reads done; reuse LA
#pragma unroll
    for (int mi = 0; mi < 4; mi++) {
#pragma unroll
        for (int r = 0; r < 4; r++) {
            float v = acc[mi][r] + bv;
            v = v > 0.f ? v : 0.f;
            LA[(mi * 16 + q * 4 + r) * 72 + w * 16 + m] = f2b(v);
        }
    }
    __syncthreads();
    const int fl = *flag;
    {
        const int c8 = t & 7;
#pragma unroll
        for (int pass = 0; pass < 2; pass++) {
            const int rt = pass * 32 + (t >> 3);
            const int row = r0 + rt;
            bool mk = fl ? (((const unsigned char*)maskp)[row] != 0)
                         : (((const int*)maskp)[row] != 0);
            if (mk == (bn == 0)) {
                *(uint4*)&G[(size_t)row * 192 + 128 + c8 * 8] =
                    *(const uint4*)&LA[rt * 72 + c8 * 8];
            }
        }
    }
}

// ---------------------------------------------------------------------------
// Direct GEMM: MT rows x 64 cols/block, grid nbm*4 (bn=bid&3), N-out=256.
// Whole-K A (2 bf16 segments) in LDS once, ONE barrier, B in <=8-kstep
// register chunks. MODE 1: relu -> bf16 CH via LDS-staged 128B/row writes.
// MODE 3: fused classifier -> atomic out.
// ---------------------------------------------------------------------------
template <int MODE, int KT, int KE0, int MT>
__global__ __launch_bounds__(256, 2) void k_g(
    const u16* __restrict__ A0, int s0, const u16* __restrict__ A1, int s1,
    const u16* __restrict__ Bh, const u16* __restrict__ Bl,
    const float* __restrict__ bias,
    u16* __restrict__ CH, float* __restrict__ outp, const float* __restrict__ wc,
    int M) {
    constexpr int MI = MT / 16;
    __shared__ __align__(16) u16 LA[MI * KT * 68 * 8];
    const int t = threadIdx.x;
    const int bm = blockIdx.x >> 2, bn = blockIdx.x & 3;
    const int lane = t & 63, w = t >> 6;
    const int m = lane & 15, q = lane >> 4;
    const int r0 = bm * MT;
    const int col = bn * 64 + w * 16 + m;
    const int K = KT * 32;

    {
        constexpr int TPR = 256 / MT;
        constexpr int SPT = KT / TPR;
        const int rr = t / TPR, sub = t & (TPR - 1);
        int arow = r0 + rr; if (arow >= M) arow = M - 1;
        const int mi = rr >> 4, r15 = rr & 15;
#pragma unroll
        for (int s = 0; s < SPT; s++) {
            const int kc = sub * SPT + s;
#pragma unroll
            for (int q2 = 0; q2 < 4; q2++) {
                const int c = kc * 32 + q2 * 8;
                uint4 v = (c < KE0 * 32)
                              ? *(const uint4*)&A0[(size_t)arow * s0 + c]
                              : *(const uint4*)&A1[(size_t)arow * s1 + (c - KE0 * 32)];
                *(uint4*)&LA[((mi * KT + kc) * 68 + 16 * q2 + r15) * 8] = v;
            }
        }
    }
    __syncthreads();

    f32x4 acc[MI] = {};
#pragma unroll
    for (int kb = 0; kb < KT; kb += 8) {
        constexpr int KC8 = (KT < 8) ? KT : 8;
        const int KC = (KT - kb < KC8) ? (KT - kb) : KC8;
        short8 bf[KC8][2];
#pragma unroll
        for (int k0 = 0; k0 < KC8; k0++) {
            if (k0 < KC) {
                size_t b = (size_t)col * K + (kb + k0) * 32 + q * 8;
                bf[k0][0] = *(const short8*)&Bh[b];
                bf[k0][1] = *(const short8*)&Bl[b];
            }
        }
#pragma unroll
        for (int mi = 0; mi < MI; mi++) {
#pragma unroll
            for (int k0 = 0; k0 < KC8; k0++) {
                if (k0 < KC) {
                    short8 af = *(const short8*)&LA[((mi * KT + kb + k0) * 68 + lane) * 8];
                    acc[mi] = __builtin_amdgcn_mfma_f32_16x16x32_bf16(af, bf[k0][0], acc[mi], 0, 0, 0);
                    acc[mi] = __builtin_amdgcn_mfma_f32_16x16x32_bf16(af, bf[k0][1], acc[mi], 0, 0, 0);
                }
            }
        }
    }

    const float bv = bias[col];
    if (MODE == 1) {
        __syncthreads();
#pragma unroll
        for (int mi = 0; mi < MI; mi++) {
#pragma unroll
            for (int r = 0; r < 4; r++) {
                float v = acc[mi][r] + bv;
                v = v > 0.f ? v : 0.f;
                LA[(mi * 16 + q * 4 + r) * 72 + w * 16 + m] = f2b(v);
            }
        }
        __syncthreads();
        const int c8 = t & 7;
#pragma unroll
        for (int pass = 0; pass < MT / 32; pass++) {
            const int rt = pass * 32 + (t >> 3);
            const int row = r0 + rt;
            if (row < M) {
                *(uint4*)&CH[(size_t)row * 256 + bn * 64 + c8 * 8] =
                    *(const uint4*)&LA[rt * 72 + c8 * 8];
            }
        }
    } else {
        const float w0 = wc[col * 2], w1 = wc[col * 2 + 1];
#pragma unroll
        for (int mi = 0; mi < MI; mi++) {
#pragma unroll
            for (int r = 0; r < 4; r++) {
                int row = r0 + mi * 16 + q * 4 + r;
                float v = acc[mi][r] + bv;
                float p0 = v * w0, p1 = v * w1;
#pragma unroll
                for (int s = 1; s < 16; s <<= 1) {
                    p0 += __shfl_xor(p0, s);
                    p1 += __shfl_xor(p1, s);
                }
                if (m == 0 && row < M) {
                    atomicAdd(&outp[row * 2], p0);
                    atomicAdd(&outp[row * 2 + 1], p1);
                }
            }
        }
    }
}

// --- layer-0 mean-agg: wave/dst over G rows (384B), 4-edge pipelined -------
__global__ void k_agg0(const u16* __restrict__ G, const int* __restrict__ off,
                       const int* __restrict__ eidx, u16* __restrict__ aggH) {
    int wid = (blockIdx.x * blockDim.x + threadIdx.x) >> 6;
    int lane = threadIdx.x & 63;
    if (wid >= N1v) return;
    int b = off[wid], e = off[wid + 1];
    float f0 = 0.f, f1 = 0.f, p0 = 0.f;
    for (int base = b; base < e; base += 64) {
        int li = base + lane;
        int idx = eidx[li < e ? li : (e - 1)];
        int nch = e - base; if (nch > 64) nch = 64;
        int j = 0;
        for (; j + 4 <= nch; j += 4) {
            int sa = __shfl(idx, j), sb = __shfl(idx, j + 1);
            int sc = __shfl(idx, j + 2), sd = __shfl(idx, j + 3);
            const u16* ra = &G[(size_t)sa * 192];
            const u16* rb = &G[(size_t)sb * 192];
            const u16* rc = &G[(size_t)sc * 192];
            const u16* rd = &G[(size_t)sd * 192];
            unsigned fa = *(const unsigned*)&ra[2 * lane];
            unsigned fb = *(const unsigned*)&rb[2 * lane];
            unsigned fc = *(const unsigned*)&rc[2 * lane];
            unsigned fd = *(const unsigned*)&rd[2 * lane];
            u16 pa = ra[128 + lane], pb = rb[128 + lane];
            u16 pc = rc[128 + lane], pd = rd[128 + lane];
            f0 += b2f((u16)fa) + b2f((u16)fb) + b2f((u16)fc) + b2f((u16)fd);
            f1 += b2f((u16)(fa >> 16)) + b2f((u16)(fb >> 16)) +
                  b2f((u16)(fc >> 16)) + b2f((u16)(fd >> 16));
            p0 += b2f(pa) + b2f(pb) + b2f(pc) + b2f(pd);
        }
        for (; j < nch; j++) {
            int s = __shfl(idx, j);
            const u16* row = &G[(size_t)s * 192];
            unsigned fv = *(const unsigned*)&row[2 * lane];
            f0 += b2f((u16)fv);
            f1 += b2f((u16)(fv >> 16));
            p0 += b2f(row[128 + lane]);
        }
    }
    int deg = e - b;
    float inv = 1.0f / (float)(deg > 1 ? deg : 1);
    size_t rb2 = (size_t)wid * 192;
    *(unsigned*)&aggH[rb2 + 2 * lane] =
        (unsigned)f2b(f0 * inv) | ((unsigned)f2b(f1 * inv) << 16);
    aggH[rb2 + 128 + lane] = f2b(p0 * inv);
}

// --- layer-1 mean-agg: wave/dst over h1H rows (512B), 4-edge pipelined -----
__global__ void k_agg1(const u16* __restrict__ h1H, const int* __restrict__ off,
                       const int* __restrict__ eidx, u16* __restrict__ aggH) {
    int wid = (blockIdx.x * blockDim.x + threadIdx.x) >> 6;
    int lane = threadIdx.x & 63;
    if (wid >= N2v) return;
    int b = off[wid], e = off[wid + 1];
    float a0 = 0.f, a1 = 0.f, a2 = 0.f, a3 = 0.f;
    for (int base = b; base < e; base += 64) {
        int li = base + lane;
        int idx = eidx[li < e ? li : (e - 1)];
        int nch = e - base; if (nch > 64) nch = 64;
        int j = 0;
        for (; j + 4 <= nch; j += 4) {
            int sa = __shfl(idx, j), sb = __shfl(idx, j + 1);
            int sc = __shfl(idx, j + 2), sd = __shfl(idx, j + 3);
            const u16* ra = &h1H[(size_t)sa * 256];
            const u16* rb = &h1H[(size_t)sb * 256];
            const u16* rc = &h1H[(size_t)sc * 256];
            const u16* rd = &h1H[(size_t)sd * 256];
            unsigned va0 = *(const unsigned*)&ra[2 * lane];
            unsigned vb0 = *(const unsigned*)&rb[2 * lane];
            unsigned vc0 = *(const unsigned*)&rc[2 * lane];
            unsigned vd0 = *(const unsigned*)&rd[2 * lane];
            unsigned va1 = *(const unsigned*)&ra[128 + 2 * lane];
            unsigned vb1 = *(const unsigned*)&rb[128 + 2 * lane];
            unsigned vc1 = *(const unsigned*)&rc[128 + 2 * lane];
            unsigned vd1 = *(const unsigned*)&rd[128 + 2 * lane];
            a0 += b2f((u16)va0) + b2f((u16)vb0) + b2f((u16)vc0) + b2f((u16)vd0);
            a1 += b2f((u16)(va0 >> 16)) + b2f((u16)(vb0 >> 16)) +
                  b2f((u16)(vc0 >> 16)) + b2f((u16)(vd0 >> 16));
            a2 += b2f((u16)va1) + b2f((u16)vb1) + b2f((u16)vc1) + b2f((u16)vd1);
            a3 += b2f((u16)(va1 >> 16)) + b2f((u16)(vb1 >> 16)) +
                  b2f((u16)(vc1 >> 16)) + b2f((u16)(vd1 >> 16));
        }
        for (; j < nch; j++) {
            int s = __shfl(idx, j);
            const u16* row = &h1H[(size_t)s * 256];
            unsigned v0 = *(const unsigned*)&row[2 * lane];
            unsigned v1 = *(const unsigned*)&row[128 + 2 * lane];
            a0 += b2f((u16)v0); a1 += b2f((u16)(v0 >> 16));
            a2 += b2f((u16)v1); a3 += b2f((u16)(v1 >> 16));
        }
    }
    int deg = e - b;
    float inv = 1.0f / (float)(deg > 1 ? deg : 1);
    size_t rb2 = (size_t)wid * 256;
    *(unsigned*)&aggH[rb2 + 2 * lane] =
        (unsigned)f2b(a0 * inv) | ((unsigned)f2b(a1 * inv) << 16);
    *(unsigned*)&aggH[rb2 + 128 + 2 * lane] =
        (unsigned)f2b(a2 * inv) | ((unsigned)f2b(a3 * inv) << 16);
}

extern "C" void kernel_launch(void* const* d_in, const int* in_sizes, int n_in,
                              void* d_out, int out_size, void* d_ws, size_t ws_size,
                              hipStream_t stream) {
    const float* features = (const float*)d_in[0];
    const void* maskp     = d_in[1];
    const int* src0       = (const int*)d_in[2];
    const int* dst0       = (const int*)d_in[3];
    const int* src1       = (const int*)d_in[4];
    const int* dst1       = (const int*)d_in[5];
    const float* w_pin    = (const float*)d_in[7];
    const float* b_pin    = (const float*)d_in[8];
    const float* w_pout   = (const float*)d_in[9];
    const float* b_pout   = (const float*)d_in[10];
    const float* w_self0  = (const float*)d_in[11];
    const float* w_neigh0 = (const float*)d_in[12];
    const float* b0       = (const float*)d_in[13];
    const float* w_self1  = (const float*)d_in[14];
    const float* w_neigh1 = (const float*)d_in[15];
    const float* b1       = (const float*)d_in[16];
    const float* w_cls    = (const float*)d_in[17];
    const float* b_cls    = (const float*)d_in[18];
    float* out = (float*)d_out;
    (void)in_sizes; (void)n_in; (void)out_size; (void)ws_size;

    char* ws = (char*)d_ws;
    size_t o = 0;
    auto alloc = [&](size_t bytes) { size_t r = o; o += (bytes + 255) & ~(size_t)255; return r; };
    // zeroed block (one memset)
    size_t o_flag = alloc(4);
    size_t o_cnt0 = alloc(N1v * 4);
    size_t o_cur0 = alloc(N1v * 4);
    size_t o_cnt1 = alloc(N2v * 4);
    size_t o_cur1 = alloc(N2v * 4);
    size_t zero_end = o;
    // rest
    size_t o_G    = alloc((size_t)N0v * 192 * 2);   // 76.8 MB
    size_t o_aggH = alloc((size_t)N1v * 192 * 2);
    size_t o_h1H  = alloc((size_t)N1v * 256 * 2);
    size_t o_ag1H = alloc((size_t)N2v * 256 * 2);
    size_t o_wtph = alloc(128 * 128 * 2), o_wtpl = alloc(128 * 128 * 2);
    size_t o_wt0h = alloc(256 * 384 * 2), o_wt0l = alloc(256 * 384 * 2);
    size_t o_wt1h = alloc(256 * 512 * 2), o_wt1l = alloc(256 * 512 * 2);
    size_t o_off0 = alloc((N1v + 1) * 4);
    size_t o_off1 = alloc((N2v + 1) * 4);
    size_t o_ei0  = alloc((size_t)E0v * 4);
    size_t o_ei1  = alloc((size_t)E1v * 4);
    size_t o_tsum = alloc(TBL * 4);

    int* flag = (int*)(ws + o_flag);
    int* cnt0 = (int*)(ws + o_cnt0);
    int* cur0 = (int*)(ws + o_cur0);
    int* cnt1 = (int*)(ws + o_cnt1);
    int* cur1 = (int*)(ws + o_cur1);
    u16* G     = (u16*)(ws + o_G);
    u16* aggH  = (u16*)(ws + o_aggH);
    u16* h1H   = (u16*)(ws + o_h1H);
    u16* ag1H  = (u16*)(ws + o_ag1H);
    u16* WTph = (u16*)(ws + o_wtph);
    u16* WTpl = (u16*)(ws + o_wtpl);
    u16* WT0h = (u16*)(ws + o_wt0h);
    u16* WT0l = (u16*)(ws + o_wt0l);
    u16* WT1h = (u16*)(ws + o_wt1h);
    u16* WT1l = (u16*)(ws + o_wt1l);
    int* off0 = (int*)(ws + o_off0);
    int* off1 = (int*)(ws + o_off1);
    int* ei0  = (int*)(ws + o_ei0);
    int* ei1  = (int*)(ws + o_ei1);
    int* tsum = (int*)(ws + o_tsum);

    // 1: zero flag + counters in one memset
    hipMemsetAsync(ws + o_flag, 0, zero_end - o_flag, stream);

    // 2: prep (detect + weight splits + out init + degree counts)
    k_prep<<<1024, 256, 0, stream>>>((const unsigned*)maskp, flag,
                                     w_pin, w_pout, WTph, WTpl,
                                     w_self0, w_neigh0, WT0h, WT0l,
                                     w_self1, w_neigh1, WT1h, WT1l,
                                     b_cls, out, dst0, dst1, cnt0, cnt1);

    // 3-4: hierarchical scan (both graphs)
    k_scan_a<<<TBL, 256, 0, stream>>>(cnt0, off0, cnt1, off1, tsum);
    k_scan_c<<<TBL, 256, 0, stream>>>(off0, off1, tsum);

    // 5: edge scatter
    k_scatter2<<<1024, 256, 0, stream>>>(src0, dst0, off0, cur0, ei0,
                                         src1, dst1, off1, cur1, ei1);

    // 6: prompt GEMM -> G[N0,192] = [featH | psel]
    k_gemm_p<<<(N0v / 64) * 2, 256, 0, stream>>>(features, WTph, WTpl,
                                                 b_pin, b_pout, maskp, flag, G);

    // 7: layer-0 mean agg -> aggH[N1,192]
    k_agg0<<<(N1v + 3) / 4, 256, 0, stream>>>(G, off0, ei0, aggH);

    // 8: h1 = relu([G | agg] @ WT0 + b0) -> h1H[N1,256]  (K=384: 6+6 ksteps)
    k_g<1, 12, 6, 64><<<((N1v + 63) / 64) * 4, 256, 0, stream>>>(
        G, 192, aggH, 192, WT0h, WT0l, b0, h1H, nullptr, nullptr, N1v);

    // 9: layer-1 mean agg -> ag1H[N2,256]
    k_agg1<<<(N2v + 3) / 4, 256, 0, stream>>>(h1H, off1, ei1, ag1H);

    // 10: logits = ([h1|agg1] @ WT1 + b1) @ w_cls + b_cls  (fused, K=512)
    k_g<3, 16, 8, 32><<<((N2v + 31) / 32) * 4, 256, 0, stream>>>(
        h1H, 256, ag1H, 256, WT1h, WT1l, b1, nullptr, out, w_cls, N2v);
}

// Round 9
// 447.755 us; speedup vs baseline: 1.4850x; 1.0122x over previous
//
#include <hip/hip_runtime.h>

// ---------------------------------------------------------------------------
// GNNWithPrompt, f32 I/O. Hi-only bf16 activations, hi+lo bf16 weights.
// GEMMs: whole-K LDS A-tile, frag stride 66 (uniform-bank staging), ONE
// barrier, 2 col-frags/wave (4 MFMA per ds_read), B in 4-kstep register
// chunks (64 VGPR live). Sector-full coalesced stores everywhere.
// CSR: 2-kernel hierarchical scan. Mean-agg: index broadcast + 4-edge
// pipelining. 10 dispatches.
// ---------------------------------------------------------------------------

#define N0v 200000
#define N1v 50000
#define N2v 10000
#define E0v 800000
#define E1v 160000
#define TB0 49            // graph0 scan tiles (1024 each)
#define TB1 10            // graph1 scan tiles
#define TBL (TB0 + TB1)

using u16 = unsigned short;
typedef __attribute__((ext_vector_type(8))) short short8;
typedef __attribute__((ext_vector_type(4))) float f32x4;

__device__ __forceinline__ float b2f(u16 u) {
    union { unsigned int i; float f; } v; v.i = ((unsigned int)u) << 16; return v.f;
}
__device__ __forceinline__ u16 f2b(float f) {  // round-to-nearest-even
    union { float f; unsigned int i; } v; v.f = f;
    return (u16)((v.i + 0x7fffu + ((v.i >> 16) & 1u)) >> 16);
}
__device__ __forceinline__ void split2(float f, u16& h, u16& l) {
    h = f2b(f);
    l = f2b(f - b2f(h));
}

// --- prep: detect + weight splits + out=bias init + BOTH degree counts -----
__global__ void k_prep(const unsigned* mask, int* flag,
                       const float* w_pin, const float* w_pout, u16* WTph, u16* WTpl,
                       const float* ws0, const float* wn0, u16* WT0h, u16* WT0l,
                       const float* ws1, const float* wn1, u16* WT1h, u16* WT1l,
                       const float* bc, float* outp,
                       const int* __restrict__ dst0, const int* __restrict__ dst1,
                       int* cnt0, int* cnt1) {
    const int R0 = 50000;             // detect words
    const int R1 = R0 + 128 * 128;    // prompt WT
    const int R2 = R1 + 256 * 384;    // layer0 WT
    const int R3 = R2 + 256 * 512;    // layer1 WT
    const int R4 = R3 + 2 * N2v;      // out bias init
    const int R5 = R4 + E0v;          // count graph 0
    const int R6 = R5 + E1v;          // count graph 1
    for (int i = blockIdx.x * blockDim.x + threadIdx.x; i < R6;
         i += gridDim.x * blockDim.x) {
        if (i < R0) {
            if (mask[i] > 1u) atomicOr(flag, 1);
        } else if (i < R1) {
            int j = i - R0, n = j >> 7, k = j & 127;
            float f = (n < 64) ? w_pin[k * 64 + n] : w_pout[k * 64 + (n - 64)];
            split2(f, WTph[j], WTpl[j]);
        } else if (i < R2) {
            int j = i - R1, n = j / 384, k = j % 384;
            float f = (k < 192) ? ws0[k * 256 + n] : wn0[(k - 192) * 256 + n];
            split2(f, WT0h[j], WT0l[j]);
        } else if (i < R3) {
            int j = i - R2, n = j >> 9, k = j & 511;
            float f = (k < 256) ? ws1[k * 256 + n] : wn1[(k - 256) * 256 + n];
            split2(f, WT1h[j], WT1l[j]);
        } else if (i < R4) {
            int j = i - R3;
            outp[j] = bc[j & 1];
        } else if (i < R5) {
            atomicAdd(&cnt0[dst0[i - R4]], 1);
        } else {
            atomicAdd(&cnt1[dst1[i - R5]], 1);
        }
    }
}

// --- hierarchical scan, pass A: per-tile local exclusive scan + tile sums --
__global__ __launch_bounds__(256) void k_scan_a(const int* __restrict__ cnt0,
                                                int* __restrict__ off0,
                                                const int* __restrict__ cnt1,
                                                int* __restrict__ off1,
                                                int* __restrict__ tsum) {
    __shared__ int sd[256];
    const int t = threadIdx.x;
    const int blk = blockIdx.x;
    const int g1 = (blk >= TB0);
    const int b = g1 ? blk - TB0 : blk;
    const int n = g1 ? N2v : N1v;
    const int* cnt = g1 ? cnt1 : cnt0;
    int* off = g1 ? off1 : off0;
    const int i0 = b * 1024 + t * 4;
    int c[4] = {0, 0, 0, 0};
    if (i0 + 3 < n) {
        *(int4*)c = *(const int4*)&cnt[i0];
    } else {
        for (int j = 0; j < 4; j++) if (i0 + j < n) c[j] = cnt[i0 + j];
    }
    int s = c[0] + c[1] + c[2] + c[3];
    sd[t] = s;
    __syncthreads();
#pragma unroll
    for (int d = 1; d < 256; d <<= 1) {
        int v = (t >= d) ? sd[t - d] : 0;
        __syncthreads();
        sd[t] += v;
        __syncthreads();
    }
    int run = sd[t] - s;  // exclusive prefix within tile
    int o4[4];
#pragma unroll
    for (int j = 0; j < 4; j++) { o4[j] = run; run += c[j]; }
    if (i0 + 3 < n) *(int4*)&off[i0] = *(const int4*)o4;
    else for (int j = 0; j < 4; j++) if (i0 + j < n) off[i0 + j] = o4[j];
    if (t == 255) tsum[blk] = sd[255];
}

// --- hierarchical scan, pass C: add tile bases (segmented), sentinels ------
__global__ __launch_bounds__(256) void k_scan_c(int* __restrict__ off0,
                                                int* __restrict__ off1,
                                                const int* __restrict__ tsum) {
    __shared__ int lbase;
    const int t = threadIdx.x;
    const int blk = blockIdx.x;
    const int g1 = (blk >= TB0);
    const int b = g1 ? blk - TB0 : blk;
    const int n = g1 ? N2v : N1v;
    int* off = g1 ? off1 : off0;
    if (t < 64) {
        int v = (t < TBL) ? tsum[t] : 0;
        int incl = v;
#pragma unroll
        for (int d = 1; d < 64; d <<= 1) {
            int u = __shfl_up(incl, d);
            if (t >= d) incl += u;
        }
        int total0 = __shfl(incl, TB0 - 1);      // sum of graph-0 tiles
        if (t == blk) lbase = (incl - v) - (g1 ? total0 : 0);
    }
    __syncthreads();
    const int base = lbase;
    const int i0 = b * 1024 + t * 4;
    if (i0 + 3 < n) {
        int4 v = *(int4*)&off[i0];
        v.x += base; v.y += base; v.z += base; v.w += base;
        *(int4*)&off[i0] = v;
    } else {
        for (int j = 0; j < 4; j++) if (i0 + j < n) off[i0 + j] += base;
    }
    if (blk == 0 && t == 0) { off0[N1v] = E0v; off1[N2v] = E1v; }
}

__global__ void k_scatter2(const int* __restrict__ src0, const int* __restrict__ dst0,
                           const int* __restrict__ off0, int* cur0, int* ei0,
                           const int* __restrict__ src1, const int* __restrict__ dst1,
                           const int* __restrict__ off1, int* cur1, int* ei1) {
    for (int i = blockIdx.x * blockDim.x + threadIdx.x; i < E0v + E1v;
         i += gridDim.x * blockDim.x) {
        if (i < E0v) {
            int d = dst0[i];
            ei0[off0[d] + atomicAdd(&cur0[d], 1)] = src0[i];
        } else {
            int d = dst1[i - E0v];
            ei1[off1[d] + atomicAdd(&cur1[d], 1)] = src1[i - E0v];
        }
    }
}

// ---------------------------------------------------------------------------
// Prompt GEMM: 64 rows x 128 cols per block (single N pass), grid 3125.
// Wave owns 32 cols (2 frags). Whole-K (4 ksteps) A in LDS, ONE barrier.
// featH side-store: 4 rows x 256B contiguous per instr. Epilogue: full
// 64x128 tile in LDS, mask-select 128B line per row.
// ---------------------------------------------------------------------------
__global__ __launch_bounds__(256, 3) void k_gemm_p(
    const float* __restrict__ A, const u16* __restrict__ Bh, const u16* __restrict__ Bl,
    const float* __restrict__ b_pin, const float* __restrict__ b_pout,
    const void* maskp, const int* __restrict__ flag, u16* __restrict__ G) {
    __shared__ __align__(16) u16 LA[8704];  // staging 16 frags x66 grp; epi 64x136
    const int t = threadIdx.x;
    const int bm = blockIdx.x;
    const int lane = t & 63, w = t >> 6;
    const int m = lane & 15, q = lane >> 4;
    const int r0 = bm * 64;
    const int colbase = w * 32;

    // B frags: 2 cols x 4 ksteps x 2 planes = 64 VGPR
    short8 bf[2][4][2];
#pragma unroll
    for (int nt = 0; nt < 2; nt++)
#pragma unroll
        for (int k0 = 0; k0 < 4; k0++) {
            size_t b = (size_t)(colbase + nt * 16 + m) * 128 + k0 * 32 + q * 8;
            bf[nt][k0][0] = *(const short8*)&Bh[b];
            bf[nt][k0][1] = *(const short8*)&Bl[b];
        }

    // stage A (f32 -> hi bf16) + featH store
    {
        const int r15 = t >> 4, ch = t & 15;
        const int k0 = ch >> 2, q2 = ch & 3;
#pragma unroll
        for (int p = 0; p < 4; p++) {
            const int row = r0 + r15 + 16 * p;
            const float* ap = &A[(size_t)row * 128 + ch * 8];
            float4 v0 = *(const float4*)ap, v1 = *(const float4*)(ap + 4);
            u16 h8[8];
            h8[0] = f2b(v0.x); h8[1] = f2b(v0.y); h8[2] = f2b(v0.z); h8[3] = f2b(v0.w);
            h8[4] = f2b(v1.x); h8[5] = f2b(v1.y); h8[6] = f2b(v1.z); h8[7] = f2b(v1.w);
            *(uint4*)&G[(size_t)row * 192 + ch * 8] = *(const uint4*)h8;
            *(uint4*)&LA[((p * 4 + k0) * 66 + 16 * q2 + r15) * 8] = *(const uint4*)h8;
        }
    }
    __syncthreads();

    f32x4 acc[4][2] = {};
#pragma unroll
    for (int mi = 0; mi < 4; mi++) {
#pragma unroll
        for (int k0 = 0; k0 < 4; k0++) {
            short8 af = *(const short8*)&LA[((mi * 4 + k0) * 66 + lane) * 8];
#pragma unroll
            for (int nt = 0; nt < 2; nt++) {
                acc[mi][nt] = __builtin_amdgcn_mfma_f32_16x16x32_bf16(af, bf[nt][k0][0], acc[mi][nt], 0, 0, 0);
                acc[mi][nt] = __builtin_amdgcn_mfma_f32_16x16x32_bf16(af, bf[nt][k0][1], acc[mi][nt], 0, 0, 0);
            }
        }
    }

    // epilogue tile (64 x 128 u16, stride 136)
    float bv[2];
#pragma unroll
    for (int nt = 0; nt < 2; nt++) {
        int col = colbase + nt * 16 + m;
        bv[nt] = (col < 64) ? b_pin[col] : b_pout[col - 64];
    }
    __syncthreads();
#pragma unroll
    for (int mi = 0; mi < 4; mi++)
#pragma unroll
        for (int nt = 0; nt < 2; nt++)
#pragma unroll
            for (int r = 0; r < 4; r++) {
                float v = acc[mi][nt][r] + bv[nt];
                v = v > 0.f ? v : 0.f;
                LA[(mi * 16 + q * 4 + r) * 136 + colbase + nt * 16 + m] = f2b(v);
            }
    __syncthreads();
    const int fl = *flag;
    {
        const int c8 = t & 7;
#pragma unroll
        for (int pass = 0; pass < 2; pass++) {
            const int rt = pass * 32 + (t >> 3);
            const int row = r0 + rt;
            bool mk = fl ? (((const unsigned char*)maskp)[row] != 0)
                         : (((const int*)maskp)[row] != 0);
            const int src = mk ? 0 : 64;
            *(uint4*)&G[(size_t)row * 192 + 128 + c8 * 8] =
                *(const uint4*)&LA[rt * 136 + src + c8 * 8];
        }
    }
}

// ---------------------------------------------------------------------------
// Direct GEMM: MT rows x 128 cols/block, grid nbm*2 (bn=bid&1), N-out=256.
// Wave owns 32 cols (2 frags). Whole-K A (2 bf16 segments) in LDS once,
// ONE barrier, B in 4-kstep register chunks. MODE 1: relu -> bf16 CH via
// LDS-staged 256B/row writes. MODE 3: fused classifier -> atomic out.
// ---------------------------------------------------------------------------
template <int MODE, int KT, int KE0, int MT>
__global__ __launch_bounds__(256, 3) void k_g(
    const u16* __restrict__ A0, int s0, const u16* __restrict__ A1, int s1,
    const u16* __restrict__ Bh, const u16* __restrict__ Bl,
    const float* __restrict__ bias,
    u16* __restrict__ CH, float* __restrict__ outp, const float* __restrict__ wc,
    int M) {
    constexpr int MI = MT / 16;
    __shared__ __align__(16) u16 LA[MI * KT * 66 * 8];
    const int t = threadIdx.x;
    const int bm = blockIdx.x >> 1, bn = blockIdx.x & 1;
    const int lane = t & 63, w = t >> 6;
    const int m = lane & 15, q = lane >> 4;
    const int r0 = bm * MT;
    const int colbase = bn * 128 + w * 32;
    const int K = KT * 32;

    // stage whole-K A-tile (frag stride 66 -> uniform banks)
    {
        constexpr int TPR = 256 / MT;
        constexpr int SPT = KT / TPR;
        const int rr = t / TPR, sub = t & (TPR - 1);
        int arow = r0 + rr; if (arow >= M) arow = M - 1;
        const int mi = rr >> 4, r15 = rr & 15;
#pragma unroll
        for (int s = 0; s < SPT; s++) {
            const int kc = sub * SPT + s;
#pragma unroll
            for (int q2 = 0; q2 < 4; q2++) {
                const int c = kc * 32 + q2 * 8;
                uint4 v = (c < KE0 * 32)
                              ? *(const uint4*)&A0[(size_t)arow * s0 + c]
                              : *(const uint4*)&A1[(size_t)arow * s1 + (c - KE0 * 32)];
                *(uint4*)&LA[((mi * KT + kc) * 66 + 16 * q2 + r15) * 8] = v;
            }
        }
    }
    __syncthreads();

    f32x4 acc[MI][2] = {};
#pragma unroll 1
    for (int kb = 0; kb < KT; kb += 4) {
        short8 bf[2][4][2];
#pragma unroll
        for (int nt = 0; nt < 2; nt++)
#pragma unroll
            for (int k0 = 0; k0 < 4; k0++) {
                size_t b = (size_t)(colbase + nt * 16 + m) * K + (kb + k0) * 32 + q * 8;
                bf[nt][k0][0] = *(const short8*)&Bh[b];
                bf[nt][k0][1] = *(const short8*)&Bl[b];
            }
#pragma unroll
        for (int mi = 0; mi < MI; mi++) {
#pragma unroll
            for (int k0 = 0; k0 < 4; k0++) {
                short8 af = *(const short8*)&LA[((mi * KT + kb + k0) * 66 + lane) * 8];
#pragma unroll
                for (int nt = 0; nt < 2; nt++) {
                    acc[mi][nt] = __builtin_amdgcn_mfma_f32_16x16x32_bf16(af, bf[nt][k0][0], acc[mi][nt], 0, 0, 0);
                    acc[mi][nt] = __builtin_amdgcn_mfma_f32_16x16x32_bf16(af, bf[nt][k0][1], acc[mi][nt], 0, 0, 0);
                }
            }
        }
    }

    if (MODE == 1) {
        float bv[2];
#pragma unroll
        for (int nt = 0; nt < 2; nt++) bv[nt] = bias[colbase + nt * 16 + m];
        __syncthreads();
#pragma unroll
        for (int mi = 0; mi < MI; mi++)
#pragma unroll
            for (int nt = 0; nt < 2; nt++)
#pragma unroll
                for (int r = 0; r < 4; r++) {
                    float v = acc[mi][nt][r] + bv[nt];
                    v = v > 0.f ? v : 0.f;
                    LA[(mi * 16 + q * 4 + r) * 136 + w * 32 + nt * 16 + m] = f2b(v);
                }
        __syncthreads();
        const int c16 = t & 15;
#pragma unroll
        for (int pass = 0; pass < MT / 16; pass++) {
            const int rt = pass * 16 + (t >> 4);
            const int row = r0 + rt;
            if (row < M) {
                *(uint4*)&CH[(size_t)row * 256 + bn * 128 + c16 * 8] =
                    *(const uint4*)&LA[rt * 136 + c16 * 8];
            }
        }
    } else {
        const int ca = colbase + m, cb = colbase + 16 + m;
        const float bva = bias[ca], bvb = bias[cb];
        const float w0a = wc[ca * 2], w1a = wc[ca * 2 + 1];
        const float w0b = wc[cb * 2], w1b = wc[cb * 2 + 1];
#pragma unroll
        for (int mi = 0; mi < MI; mi++) {
#pragma unroll
            for (int r = 0; r < 4; r++) {
                int row = r0 + mi * 16 + q * 4 + r;
                float va = acc[mi][0][r] + bva;
                float vb = acc[mi][1][r] + bvb;
                float p0 = va * w0a + vb * w0b;
                float p1 = va * w1a + vb * w1b;
#pragma unroll
                for (int s = 1; s < 16; s <<= 1) {
                    p0 += __shfl_xor(p0, s);
                    p1 += __shfl_xor(p1, s);
                }
                if (m == 0 && row < M) {
                    atomicAdd(&outp[row * 2], p0);
                    atomicAdd(&outp[row * 2 + 1], p1);
                }
            }
        }
    }
}

// --- layer-0 mean-agg: wave/dst over G rows (384B), 4-edge pipelined -------
__global__ void k_agg0(const u16* __restrict__ G, const int* __restrict__ off,
                       const int* __restrict__ eidx, u16* __restrict__ aggH) {
    int wid = (blockIdx.x * blockDim.x + threadIdx.x) >> 6;
    int lane = threadIdx.x & 63;
    if (wid >= N1v) return;
    int b = off[wid], e = off[wid + 1];
    float f0 = 0.f, f1 = 0.f, p0 = 0.f;
    for (int base = b; base < e; base += 64) {
        int li = base + lane;
        int idx = eidx[li < e ? li : (e - 1)];
        int nch = e - base; if (nch > 64) nch = 64;
        int j = 0;
        for (; j + 4 <= nch; j += 4) {
            int sa = __shfl(idx, j), sb = __shfl(idx, j + 1);
            int sc = __shfl(idx, j + 2), sd = __shfl(idx, j + 3);
            const u16* ra = &G[(size_t)sa * 192];
            const u16* rb = &G[(size_t)sb * 192];
            const u16* rc = &G[(size_t)sc * 192];
            const u16* rd = &G[(size_t)sd * 192];
            unsigned fa = *(const unsigned*)&ra[2 * lane];
            unsigned fb = *(const unsigned*)&rb[2 * lane];
            unsigned fc = *(const unsigned*)&rc[2 * lane];
            unsigned fd = *(const unsigned*)&rd[2 * lane];
            u16 pa = ra[128 + lane], pb = rb[128 + lane];
            u16 pc = rc[128 + lane], pd = rd[128 + lane];
            f0 += b2f((u16)fa) + b2f((u16)fb) + b2f((u16)fc) + b2f((u16)fd);
            f1 += b2f((u16)(fa >> 16)) + b2f((u16)(fb >> 16)) +
                  b2f((u16)(fc >> 16)) + b2f((u16)(fd >> 16));
            p0 += b2f(pa) + b2f(pb) + b2f(pc) + b2f(pd);
        }
        for (; j < nch; j++) {
            int s = __shfl(idx, j);
            const u16* row = &G[(size_t)s * 192];
            unsigned fv = *(const unsigned*)&row[2 * lane];
            f0 += b2f((u16)fv);
            f1 += b2f((u16)(fv >> 16));
            p0 += b2f(row[128 + lane]);
        }
    }
    int deg = e - b;
    float inv = 1.0f / (float)(deg > 1 ? deg : 1);
    size_t rb2 = (size_t)wid * 192;
    *(unsigned*)&aggH[rb2 + 2 * lane] =
        (unsigned)f2b(f0 * inv) | ((unsigned)f2b(f1 * inv) << 16);
    aggH[rb2 + 128 + lane] = f2b(p0 * inv);
}

// --- layer-1 mean-agg: wave/dst over h1H rows (512B), 4-edge pipelined -----
__global__ void k_agg1(const u16* __restrict__ h1H, const int* __restrict__ off,
                       const int* __restrict__ eidx, u16* __restrict__ aggH) {
    int wid = (blockIdx.x * blockDim.x + threadIdx.x) >> 6;
    int lane = threadIdx.x & 63;
    if (wid >= N2v) return;
    int b = off[wid], e = off[wid + 1];
    float a0 = 0.f, a1 = 0.f, a2 = 0.f, a3 = 0.f;
    for (int base = b; base < e; base += 64) {
        int li = base + lane;
        int idx = eidx[li < e ? li : (e - 1)];
        int nch = e - base; if (nch > 64) nch = 64;
        int j = 0;
        for (; j + 4 <= nch; j += 4) {
            int sa = __shfl(idx, j), sb = __shfl(idx, j + 1);
            int sc = __shfl(idx, j + 2), sd = __shfl(idx, j + 3);
            const u16* ra = &h1H[(size_t)sa * 256];
            const u16* rb = &h1H[(size_t)sb * 256];
            const u16* rc = &h1H[(size_t)sc * 256];
            const u16* rd = &h1H[(size_t)sd * 256];
            unsigned va0 = *(const unsigned*)&ra[2 * lane];
            unsigned vb0 = *(const unsigned*)&rb[2 * lane];
            unsigned vc0 = *(const unsigned*)&rc[2 * lane];
            unsigned vd0 = *(const unsigned*)&rd[2 * lane];
            unsigned va1 = *(const unsigned*)&ra[128 + 2 * lane];
            unsigned vb1 = *(const unsigned*)&rb[128 + 2 * lane];
            unsigned vc1 = *(const unsigned*)&rc[128 + 2 * lane];
            unsigned vd1 = *(const unsigned*)&rd[128 + 2 * lane];
            a0 += b2f((u16)va0) + b2f((u16)vb0) + b2f((u16)vc0) + b2f((u16)vd0);
            a1 += b2f((u16)(va0 >> 16)) + b2f((u16)(vb0 >> 16)) +
                  b2f((u16)(vc0 >> 16)) + b2f((u16)(vd0 >> 16));
            a2 += b2f((u16)va1) + b2f((u16)vb1) + b2f((u16)vc1) + b2f((u16)vd1);
            a3 += b2f((u16)(va1 >> 16)) + b2f((u16)(vb1 >> 16)) +
                  b2f((u16)(vc1 >> 16)) + b2f((u16)(vd1 >> 16));
        }
        for (; j < nch; j++) {
            int s = __shfl(idx, j);
            const u16* row = &h1H[(size_t)s * 256];
            unsigned v0 = *(const unsigned*)&row[2 * lane];
            unsigned v1 = *(const unsigned*)&row[128 + 2 * lane];
            a0 += b2f((u16)v0); a1 += b2f((u16)(v0 >> 16));
            a2 += b2f((u16)v1); a3 += b2f((u16)(v1 >> 16));
        }
    }
    int deg = e - b;
    float inv = 1.0f / (float)(deg > 1 ? deg : 1);
    size_t rb2 = (size_t)wid * 256;
    *(unsigned*)&aggH[rb2 + 2 * lane] =
        (unsigned)f2b(a0 * inv) | ((unsigned)f2b(a1 * inv) << 16);
    *(unsigned*)&aggH[rb2 + 128 + 2 * lane] =
        (unsigned)f2b(a2 * inv) | ((unsigned)f2b(a3 * inv) << 16);
}

extern "C" void kernel_launch(void* const* d_in, const int* in_sizes, int n_in,
                              void* d_out, int out_size, void* d_ws, size_t ws_size,
                              hipStream_t stream) {
    const float* features = (const float*)d_in[0];
    const void* maskp     = d_in[1];
    const int* src0       = (const int*)d_in[2];
    const int* dst0       = (const int*)d_in[3];
    const int* src1       = (const int*)d_in[4];
    const int* dst1       = (const int*)d_in[5];
    const float* w_pin    = (const float*)d_in[7];
    const float* b_pin    = (const float*)d_in[8];
    const float* w_pout   = (const float*)d_in[9];
    const float* b_pout   = (const float*)d_in[10];
    const float* w_self0  = (const float*)d_in[11];
    const float* w_neigh0 = (const float*)d_in[12];
    const float* b0       = (const float*)d_in[13];
    const float* w_self1  = (const float*)d_in[14];
    const float* w_neigh1 = (const float*)d_in[15];
    const float* b1       = (const float*)d_in[16];
    const float* w_cls    = (const float*)d_in[17];
    const float* b_cls    = (const float*)d_in[18];
    float* out = (float*)d_out;
    (void)in_sizes; (void)n_in; (void)out_size; (void)ws_size;

    char* ws = (char*)d_ws;
    size_t o = 0;
    auto alloc = [&](size_t bytes) { size_t r = o; o += (bytes + 255) & ~(size_t)255; return r; };
    // zeroed block (one memset)
    size_t o_flag = alloc(4);
    size_t o_cnt0 = alloc(N1v * 4);
    size_t o_cur0 = alloc(N1v * 4);
    size_t o_cnt1 = alloc(N2v * 4);
    size_t o_cur1 = alloc(N2v * 4);
    size_t zero_end = o;
    // rest
    size_t o_G    = alloc((size_t)N0v * 192 * 2);   // 76.8 MB
    size_t o_aggH = alloc((size_t)N1v * 192 * 2);
    size_t o_h1H  = alloc((size_t)N1v * 256 * 2);
    size_t o_ag1H = alloc((size_t)N2v * 256 * 2);
    size_t o_wtph = alloc(128 * 128 * 2), o_wtpl = alloc(128 * 128 * 2);
    size_t o_wt0h = alloc(256 * 384 * 2), o_wt0l = alloc(256 * 384 * 2);
    size_t o_wt1h = alloc(256 * 512 * 2), o_wt1l = alloc(256 * 512 * 2);
    size_t o_off0 = alloc((N1v + 1) * 4);
    size_t o_off1 = alloc((N2v + 1) * 4);
    size_t o_ei0  = alloc((size_t)E0v * 4);
    size_t o_ei1  = alloc((size_t)E1v * 4);
    size_t o_tsum = alloc(TBL * 4);

    int* flag = (int*)(ws + o_flag);
    int* cnt0 = (int*)(ws + o_cnt0);
    int* cur0 = (int*)(ws + o_cur0);
    int* cnt1 = (int*)(ws + o_cnt1);
    int* cur1 = (int*)(ws + o_cur1);
    u16* G     = (u16*)(ws + o_G);
    u16* aggH  = (u16*)(ws + o_aggH);
    u16* h1H   = (u16*)(ws + o_h1H);
    u16* ag1H  = (u16*)(ws + o_ag1H);
    u16* WTph = (u16*)(ws + o_wtph);
    u16* WTpl = (u16*)(ws + o_wtpl);
    u16* WT0h = (u16*)(ws + o_wt0h);
    u16* WT0l = (u16*)(ws + o_wt0l);
    u16* WT1h = (u16*)(ws + o_wt1h);
    u16* WT1l = (u16*)(ws + o_wt1l);
    int* off0 = (int*)(ws + o_off0);
    int* off1 = (int*)(ws + o_off1);
    int* ei0  = (int*)(ws + o_ei0);
    int* ei1  = (int*)(ws + o_ei1);
    int* tsum = (int*)(ws + o_tsum);

    // 1: zero flag + counters in one memset
    hipMemsetAsync(ws + o_flag, 0, zero_end - o_flag, stream);

    // 2: prep (detect + weight splits + out init + degree counts)
    k_prep<<<1024, 256, 0, stream>>>((const unsigned*)maskp, flag,
                                     w_pin, w_pout, WTph, WTpl,
                                     w_self0, w_neigh0, WT0h, WT0l,
                                     w_self1, w_neigh1, WT1h, WT1l,
                                     b_cls, out, dst0, dst1, cnt0, cnt1);

    // 3-4: hierarchical scan (both graphs)
    k_scan_a<<<TBL, 256, 0, stream>>>(cnt0, off0, cnt1, off1, tsum);
    k_scan_c<<<TBL, 256, 0, stream>>>(off0, off1, tsum);

    // 5: edge scatter
    k_scatter2<<<1024, 256, 0, stream>>>(src0, dst0, off0, cur0, ei0,
                                         src1, dst1, off1, cur1, ei1);

    // 6: prompt GEMM -> G[N0,192] = [featH | psel]  (single N pass)
    k_gemm_p<<<N0v / 64, 256, 0, stream>>>(features, WTph, WTpl,
                                           b_pin, b_pout, maskp, flag, G);

    // 7: layer-0 mean agg -> aggH[N1,192]
    k_agg0<<<(N1v + 3) / 4, 256, 0, stream>>>(G, off0, ei0, aggH);

    // 8: h1 = relu([G | agg] @ WT0 + b0) -> h1H[N1,256]  (K=384: 6+6 ksteps)
    k_g<1, 12, 6, 64><<<((N1v + 63) / 64) * 2, 256, 0, stream>>>(
        G, 192, aggH, 192, WT0h, WT0l, b0, h1H, nullptr, nullptr, N1v);

    // 9: layer-1 mean agg -> ag1H[N2,256]
    k_agg1<<<(N2v + 3) / 4, 256, 0, stream>>>(h1H, off1, ei1, ag1H);

    // 10: logits = ([h1|agg1] @ WT1 + b1) @ w_cls + b_cls  (fused, K=512)
    k_g<3, 16, 8, 32><<<((N2v + 31) / 32) * 2, 256, 0, stream>>>(
        h1H, 256, ag1H, 256, WT1h, WT1l, b1, nullptr, out, w_cls, N2v);
}